// Round 2
// baseline (535.588 us; speedup 1.0000x reference)
//
#include <hip/hip_runtime.h>

// Problem constants
#define B_ 8
#define N_ 1024
#define F_ 256
#define O_ 256

typedef unsigned short u16;
typedef unsigned int u32;
typedef __attribute__((ext_vector_type(8))) short bf8;   // 8 bf16 (4 VGPRs) MFMA frag
typedef __attribute__((ext_vector_type(4))) float f4;    // 4 fp32 MFMA acc

__device__ __forceinline__ u16 f2bf(float f) {
  union { float f; u32 u; } c; c.f = f;
  u32 u = c.u;
  u32 r = u + 0x7FFFu + ((u >> 16) & 1u);  // RNE
  return (u16)(r >> 16);
}

// ---------------------------------------------------------------------------
// K0: convert x fp32 -> bf16 (for the MFMA Whs path only).
__global__ void k_cvt(const float* __restrict__ x, u16* __restrict__ xb) {
  int idx = (blockIdx.x * 256 + threadIdx.x) * 4;  // 2048 blocks cover 2M elems
  float4 v = *(const float4*)&x[idx];
  u16 o[4] __attribute__((aligned(8)));
  o[0] = f2bf(v.x); o[1] = f2bf(v.y); o[2] = f2bf(v.z); o[3] = f2bf(v.w);
  *(uint2*)&xb[idx] = *(uint2*)o;
}

// ---------------------------------------------------------------------------
// K1a: transpose W (d,h,f,o) fp32 -> Wt (d,h,o,f) bf16, so MFMA B-frags
// read 8 contiguous k(=f) elements from LDS.
__global__ void k_transpose(const float* __restrict__ W, u16* __restrict__ Wt) {
  __shared__ u16 t[64][72];  // pad 64->72 keeps 16B alignment, breaks conflicts
  int dh = blockIdx.y;
  int tile = blockIdx.x;
  int f0 = (tile >> 2) * 64, o0 = (tile & 3) * 64;
  const float* src = W + dh * 65536;
  u16* dst = Wt + dh * 65536;
  int tdx = threadIdx.x;
  for (int i = 0; i < 2; ++i) {
    int c = i * 256 + tdx;                  // 0..511 chunks of 8 elems
    int row = c >> 3, cc = (c & 7) * 8;
    float4 v0 = *(const float4*)&src[(f0 + row) * 256 + o0 + cc];
    float4 v1 = *(const float4*)&src[(f0 + row) * 256 + o0 + cc + 4];
    u16 tmp[8] __attribute__((aligned(16)));
    tmp[0] = f2bf(v0.x); tmp[1] = f2bf(v0.y); tmp[2] = f2bf(v0.z); tmp[3] = f2bf(v0.w);
    tmp[4] = f2bf(v1.x); tmp[5] = f2bf(v1.y); tmp[6] = f2bf(v1.z); tmp[7] = f2bf(v1.w);
    *(uint4*)&t[row][cc] = *(uint4*)tmp;
  }
  __syncthreads();
  for (int i = 0; i < 2; ++i) {
    int c = i * 256 + tdx;
    int orow = c >> 3, fc = (c & 7) * 8;
    u16 v[8] __attribute__((aligned(16)));
#pragma unroll
    for (int k = 0; k < 8; ++k) v[k] = t[fc + k][orow];
    *(uint4*)&dst[(o0 + orow) * 256 + f0 + fc] = *(uint4*)v;
  }
}

// ---------------------------------------------------------------------------
// K1b: vsrc[d][f] = sum_o W[d,1,f,o]*a[d,1,o] ; vdst with a[d,1,256+o]. fp32.
__global__ void k_vsd(const float* __restrict__ W, const float* __restrict__ a,
                      float* __restrict__ vsrc, float* __restrict__ vdst) {
  int blk = blockIdx.x;           // 1024 blocks: d = blk>>8, f = blk&255
  int d = blk >> 8, f = blk & 255;
  int o = threadIdx.x;
  int dh = d * 2 + 1;
  float w = W[(dh * 256 + f) * 256 + o];
  float as = a[dh * 512 + o];
  float ad = a[dh * 512 + 256 + o];
  float ps = w * as, pd = w * ad;
  __shared__ float red[2][4];
  for (int off = 32; off; off >>= 1) {
    ps += __shfl_down(ps, off);
    pd += __shfl_down(pd, off);
  }
  int lane = o & 63, w4 = o >> 6;
  if (lane == 0) { red[0][w4] = ps; red[1][w4] = pd; }
  __syncthreads();
  if (o == 0) vsrc[d * 256 + f] = red[0][0] + red[0][1] + red[0][2] + red[0][3];
  if (o == 1) vdst[d * 256 + f] = red[1][0] + red[1][1] + red[1][2] + red[1][3];
}

// ---------------------------------------------------------------------------
// K2: e_src[d][b][n] = x[b,n,:]·vsrc[d]; e_dst likewise. One block per (b,n). fp32.
__global__ void k_edots(const float* __restrict__ x, const float* __restrict__ vsrc,
                        const float* __restrict__ vdst, float* __restrict__ es,
                        float* __restrict__ ed) {
  int row = blockIdx.x;  // b*1024+n
  int f = threadIdx.x;
  float xv = x[(size_t)row * 256 + f];
  float p[8];
#pragma unroll
  for (int d = 0; d < 4; ++d) {
    p[d] = xv * vsrc[d * 256 + f];
    p[4 + d] = xv * vdst[d * 256 + f];
  }
#pragma unroll
  for (int v = 0; v < 8; ++v)
    for (int off = 32; off; off >>= 1) p[v] += __shfl_down(p[v], off);
  __shared__ float red[8][4];
  int lane = f & 63, w4 = f >> 6;
  if (lane == 0) {
    for (int v = 0; v < 8; ++v) red[v][w4] = p[v];
  }
  __syncthreads();
  if (f < 8) {
    float s = red[f][0] + red[f][1] + red[f][2] + red[f][3];
    int d = f & 3;
    int b = row >> 10, n = row & 1023;
    float* dstp = (f < 4) ? es : ed;
    dstp[(d * 8 + b) * 1024 + n] = s;
  }
}

// ---------------------------------------------------------------------------
// K4: pack adjacency into 4-bit masks, 4 per u32.
__global__ void k_mask(const int* __restrict__ AU, const int* __restrict__ AD,
                       const int* __restrict__ AR, const int* __restrict__ AL,
                       u32* __restrict__ mask) {
  int idx = blockIdx.x * 256 + threadIdx.x;  // 262144 u32 total
  int base = idx * 4;
  int4 au = *(const int4*)&AU[base];
  int4 ad = *(const int4*)&AD[base];
  int4 ar = *(const int4*)&AR[base];
  int4 al = *(const int4*)&AL[base];
  u32 m0 = (au.x ? 1u : 0u) | (ad.x ? 2u : 0u) | (ar.x ? 4u : 0u) | (al.x ? 8u : 0u);
  u32 m1 = (au.y ? 1u : 0u) | (ad.y ? 2u : 0u) | (ar.y ? 4u : 0u) | (al.y ? 8u : 0u);
  u32 m2 = (au.z ? 1u : 0u) | (ad.z ? 2u : 0u) | (ar.z ? 4u : 0u) | (al.z ? 8u : 0u);
  u32 m3 = (au.w ? 1u : 0u) | (ad.w ? 2u : 0u) | (ar.w ? 4u : 0u) | (al.w ? 8u : 0u);
  mask[idx] = m0 | (m1 << 8) | (m2 << 16) | (m3 << 24);
}

// ---------------------------------------------------------------------------
// K3: Whs[d][m][o] (fp32) = Xb(bf16, 8192x256) @ (W[d,0]+W[d,1]) via MFMA.
// 128x128 tile, 4 waves (2x2), each wave 4x4 16x16 tiles, K loop h=0,1 x 256.
__global__ __launch_bounds__(256, 2) void k_whsum(const u16* __restrict__ X,
                                                  const u16* __restrict__ Wt,
                                                  float* __restrict__ Whs) {
  __shared__ u16 lA[128 * 32];
  __shared__ u16 lB[128 * 32];
  int d = blockIdx.z;
  int m0 = blockIdx.y * 128;
  int o0 = blockIdx.x * 128;
  int t = threadIdx.x;
  int lane = t & 63, w = t >> 6;
  int wm = w >> 1, wn = w & 1;
  int r16 = lane & 15, q8 = (lane >> 4) * 8;
  f4 acc[4][4];
  const f4 fz = {0.f, 0.f, 0.f, 0.f};
#pragma unroll
  for (int i = 0; i < 4; ++i)
#pragma unroll
    for (int j = 0; j < 4; ++j) acc[i][j] = fz;

  for (int h = 0; h < 2; ++h) {
    const u16* Bp = Wt + (size_t)(d * 2 + h) * 65536;  // [o][f] 256x256
    for (int k0 = 0; k0 < 256; k0 += 32) {
      uint4 va[2], vb[2];
#pragma unroll
      for (int i = 0; i < 2; ++i) {
        int c = i * 256 + t;                 // 0..511 chunks (16B) of the tile
        int row = c >> 2, ko = (c & 3) * 8;  // 4 chunks per 32-wide row
        va[i] = *(const uint4*)&X[(size_t)(m0 + row) * 256 + k0 + ko];
        vb[i] = *(const uint4*)&Bp[(o0 + row) * 256 + k0 + ko];
      }
      __syncthreads();  // previous compute done reading LDS
#pragma unroll
      for (int i = 0; i < 2; ++i) {
        int c = i * 256 + t;
        *(uint4*)&lA[c * 8] = va[i];
        *(uint4*)&lB[c * 8] = vb[i];
      }
      __syncthreads();
      bf8 af[4], bfr[4];
#pragma unroll
      for (int tm = 0; tm < 4; ++tm)
        af[tm] = *(const bf8*)&lA[(wm * 64 + tm * 16 + r16) * 32 + q8];
#pragma unroll
      for (int tn = 0; tn < 4; ++tn)
        bfr[tn] = *(const bf8*)&lB[(wn * 64 + tn * 16 + r16) * 32 + q8];
#pragma unroll
      for (int tm = 0; tm < 4; ++tm)
#pragma unroll
        for (int tn = 0; tn < 4; ++tn)
          acc[tm][tn] = __builtin_amdgcn_mfma_f32_16x16x32_bf16(
              af[tm], bfr[tn], acc[tm][tn], 0, 0, 0);
    }
  }
  // epilogue: C/D layout col=lane&15, row=(lane>>4)*4+reg  [verified m89/m91]
#pragma unroll
  for (int tm = 0; tm < 4; ++tm) {
#pragma unroll
    for (int tn = 0; tn < 4; ++tn) {
      int gm_base = m0 + wm * 64 + tm * 16 + (lane >> 4) * 4;
      int go = o0 + wn * 64 + tn * 16 + r16;
#pragma unroll
      for (int r = 0; r < 4; ++r)
        Whs[((size_t)d * 8192 + gm_base + r) * 256 + go] = acc[tm][tn][r];
    }
  }
}

// ---------------------------------------------------------------------------
// K5: e_total row -> softmax -> alpha (fp32). One block per (b,i).
__global__ void k_softmax(const float* __restrict__ es, const float* __restrict__ ed,
                          const u32* __restrict__ maskw, float* __restrict__ alpha) {
  int blk = blockIdx.x;  // b*1024 + i
  int b = blk >> 10, i = blk & 1023;
  int t = threadIdx.x;
  float e0 = es[(0 * 8 + b) * 1024 + i];
  float e1 = es[(1 * 8 + b) * 1024 + i];
  float e2 = es[(2 * 8 + b) * 1024 + i];
  float e3 = es[(3 * 8 + b) * 1024 + i];
  const unsigned char* mask = (const unsigned char*)maskw;
  float et[4];
  float mx = -__builtin_inff();
#pragma unroll
  for (int jj = 0; jj < 4; ++jj) {
    int j = jj * 256 + t;
    unsigned m = mask[i * 1024 + j];
    float e;
    if (m) {
      int d = 31 - __clz((int)m);  // last direction with A!=0 wins
      float esd = d == 0 ? e0 : d == 1 ? e1 : d == 2 ? e2 : e3;
      float z = esd + ed[(d * 8 + b) * 1024 + j];
      e = z > 0.0f ? z : 0.01f * z;  // leaky_relu(0.01)
    } else {
      e = -__builtin_inff();
    }
    et[jj] = e;
    mx = fmaxf(mx, e);
  }
  __shared__ float red[4];
  __shared__ float red2[4];
  for (int off = 32; off; off >>= 1) mx = fmaxf(mx, __shfl_xor(mx, off));
  if ((t & 63) == 0) red[t >> 6] = mx;
  __syncthreads();
  mx = fmaxf(fmaxf(red[0], red[1]), fmaxf(red[2], red[3]));
  float p[4];
  float s = 0.f;
#pragma unroll
  for (int jj = 0; jj < 4; ++jj) {
    p[jj] = exp2f((et[jj] - mx) * 1.4426950408889634f);  // exp(-inf)=0 for masked
    s += p[jj];
  }
  for (int off = 32; off; off >>= 1) s += __shfl_xor(s, off);
  if ((t & 63) == 0) red2[t >> 6] = s;
  __syncthreads();
  s = red2[0] + red2[1] + red2[2] + red2[3];
  float rs = 1.0f / s;
#pragma unroll
  for (int jj = 0; jj < 4; ++jj) {
    int j = jj * 256 + t;
    alpha[((size_t)b * 1024 + i) * 1024 + j] = p[jj] * rs;
  }
}

// ---------------------------------------------------------------------------
// K6: out[b,i,o] = 0.5 * sum_j alpha[b,i,j] * sum_{d in mask} Whs[d,b,j,o]
// Tile: 32 i x 64 o per block, j staged 32 at a time. fp32 VALU. fp32 output.
__global__ __launch_bounds__(256, 2) void k_aggregate(const float* __restrict__ alpha,
                                                      const u32* __restrict__ maskw,
                                                      const float* __restrict__ Whs,
                                                      float* __restrict__ out) {
  __shared__ float sAl[32 * 32];     // [i][j]
  __shared__ u32 sMu[32 * 32 / 4];   // mask bytes [i][j]
  __shared__ float sW[4 * 32 * 64];  // [d][j][o]
  int b = blockIdx.z;
  int i0 = blockIdx.y * 32;
  int o0 = blockIdx.x * 64;
  int t = threadIdx.x;
  int ip = t >> 4, oq = (t & 15) * 4;
  int il0 = ip * 2, il1 = il0 + 1;
  f4 acc0 = {0.f, 0.f, 0.f, 0.f}, acc1 = {0.f, 0.f, 0.f, 0.f};
  const unsigned char* sM = (const unsigned char*)sMu;

  for (int j0 = 0; j0 < 1024; j0 += 32) {
    __syncthreads();  // previous iter's compute done with LDS
    {
      int col = t & 31, rbase = t >> 5;
#pragma unroll
      for (int rr = 0; rr < 4; ++rr) {
        int row = rr * 8 + rbase;
        sAl[row * 32 + col] = alpha[((size_t)b * 1024 + i0 + row) * 1024 + j0 + col];
      }
      int mrow = t >> 3, mc = t & 7;
      sMu[t] = *(const u32*)((const unsigned char*)maskw + (i0 + mrow) * 1024 + j0 + mc * 4);
#pragma unroll
      for (int ii = 0; ii < 8; ++ii) {
        int c = ii * 256 + t;  // 2048 float4 chunks
        int d = c >> 9, rem = c & 511;
        int jr = rem >> 4, oc = (rem & 15) * 4;
        *(f4*)&sW[(d * 32 + jr) * 64 + oc] =
            *(const f4*)&Whs[((size_t)d * 8192 + b * 1024 + j0 + jr) * 256 + o0 + oc];
      }
    }
    __syncthreads();
#pragma unroll 4
    for (int j = 0; j < 32; ++j) {
      f4 w0 = *(const f4*)&sW[(0 * 32 + j) * 64 + oq];
      f4 w1 = *(const f4*)&sW[(1 * 32 + j) * 64 + oq];
      f4 w2 = *(const f4*)&sW[(2 * 32 + j) * 64 + oq];
      f4 w3 = *(const f4*)&sW[(3 * 32 + j) * 64 + oq];
      float a0 = sAl[il0 * 32 + j], a1 = sAl[il1 * 32 + j];
      unsigned m0 = sM[il0 * 32 + j], m1 = sM[il1 * 32 + j];
      float c00 = (m0 & 1) ? a0 : 0.0f;
      float c01 = (m0 & 2) ? a0 : 0.0f;
      float c02 = (m0 & 4) ? a0 : 0.0f;
      float c03 = (m0 & 8) ? a0 : 0.0f;
      acc0 += c00 * w0 + c01 * w1 + c02 * w2 + c03 * w3;
      float c10 = (m1 & 1) ? a1 : 0.0f;
      float c11 = (m1 & 2) ? a1 : 0.0f;
      float c12 = (m1 & 4) ? a1 : 0.0f;
      float c13 = (m1 & 8) ? a1 : 0.0f;
      acc1 += c10 * w0 + c11 * w1 + c12 * w2 + c13 * w3;
    }
  }
  f4 r0 = acc0 * 0.5f, r1 = acc1 * 0.5f;
  *(f4*)&out[((size_t)b * 1024 + i0 + il0) * 256 + o0 + oq] = r0;
  *(f4*)&out[((size_t)b * 1024 + i0 + il1) * 256 + o0 + oq] = r1;
}

// ---------------------------------------------------------------------------
extern "C" void kernel_launch(void* const* d_in, const int* in_sizes, int n_in,
                              void* d_out, int out_size, void* d_ws, size_t ws_size,
                              hipStream_t stream) {
  const float* x = (const float*)d_in[0];
  const int* AU = (const int*)d_in[1];
  const int* AD = (const int*)d_in[2];
  const int* AR = (const int*)d_in[3];
  const int* AL = (const int*)d_in[4];
  const float* W = (const float*)d_in[5];
  const float* a = (const float*)d_in[6];
  float* out = (float*)d_out;

  char* ws = (char*)d_ws;
  // workspace layout (bytes) — total 66.3 MB (round 1 proved this fits)
  u16* Wt = (u16*)(ws + 0);                   //  1 MB  bf16 (d,h,o,f)
  float* vsrc = (float*)(ws + 1048576);       //  4 KB
  float* vdst = (float*)(ws + 1052672);       //  4 KB
  float* es = (float*)(ws + 1056768);         // 128 KB (d,b,n)
  float* ed = (float*)(ws + 1187840);         // 128 KB
  u32* maskw = (u32*)(ws + 1318912);          //  1 MB  u8 (i,j)
  float* Whs = (float*)(ws + 2367488);        // 32 MB  fp32 (d, b*n, o)
  float* alpha = (float*)(ws + 35921920);     // 32 MB  fp32 (b, i, j)
  // xb (bf16 x, 4 MB) aliases the alpha region: last read (k_whsum) precedes
  // alpha's first write (k_softmax) in stream order.
  u16* xb = (u16*)(ws + 35921920);
  if (ws_size < 69476352) return;             // need ~66.3 MB

  hipLaunchKernelGGL(k_cvt, dim3(2048), dim3(256), 0, stream, x, xb);
  hipLaunchKernelGGL(k_transpose, dim3(16, 8), dim3(256), 0, stream, W, Wt);
  hipLaunchKernelGGL(k_vsd, dim3(1024), dim3(256), 0, stream, W, a, vsrc, vdst);
  hipLaunchKernelGGL(k_edots, dim3(8192), dim3(256), 0, stream, x, vsrc, vdst, es, ed);
  hipLaunchKernelGGL(k_mask, dim3(1024), dim3(256), 0, stream, AU, AD, AR, AL, maskw);
  hipLaunchKernelGGL(k_whsum, dim3(2, 64, 4), dim3(256), 0, stream, xb, Wt, Whs);
  hipLaunchKernelGGL(k_softmax, dim3(8192), dim3(256), 0, stream, es, ed, maskw, alpha);
  hipLaunchKernelGGL(k_aggregate, dim3(4, 32, 8), dim3(256), 0, stream, alpha, maskw, Whs, out);
}

// Round 3
// 259.528 us; speedup vs baseline: 2.0637x; 2.0637x over previous
//
#include <hip/hip_runtime.h>

// Problem constants
#define B_ 8
#define N_ 1024
#define F_ 256
#define O_ 256

typedef unsigned short u16;
typedef unsigned int u32;
typedef __attribute__((ext_vector_type(8))) short bf8;   // 8 bf16 (4 VGPRs) MFMA frag
typedef __attribute__((ext_vector_type(4))) float f4;    // 4 fp32 MFMA acc

__device__ __forceinline__ u16 f2bf(float f) {
  union { float f; u32 u; } c; c.f = f;
  u32 u = c.u;
  u32 r = u + 0x7FFFu + ((u >> 16) & 1u);  // RNE
  return (u16)(r >> 16);
}

// ---------------------------------------------------------------------------
// K_zero: out is re-poisoned 0xAA before every timed launch; the aggregate
// accumulates via atomicAdd, so zero it first.
__global__ void k_zero(float* __restrict__ out) {
  int idx = (blockIdx.x * 256 + threadIdx.x) * 4;
  f4 z = {0.f, 0.f, 0.f, 0.f};
  *(f4*)&out[idx] = z;
}

// ---------------------------------------------------------------------------
// K0: convert x fp32 -> bf16 (for the MFMA Whs path only).
__global__ void k_cvt(const float* __restrict__ x, u16* __restrict__ xb) {
  int idx = (blockIdx.x * 256 + threadIdx.x) * 4;  // 2048 blocks cover 2M elems
  float4 v = *(const float4*)&x[idx];
  u16 o[4] __attribute__((aligned(8)));
  o[0] = f2bf(v.x); o[1] = f2bf(v.y); o[2] = f2bf(v.z); o[3] = f2bf(v.w);
  *(uint2*)&xb[idx] = *(uint2*)o;
}

// ---------------------------------------------------------------------------
// K1a: transpose W (d,h,f,o) fp32 -> Wt (d,h,o,f) bf16, so MFMA B-frags
// read 8 contiguous k(=f) elements from LDS.
__global__ void k_transpose(const float* __restrict__ W, u16* __restrict__ Wt) {
  __shared__ u16 t[64][72];  // pad 64->72 keeps 16B alignment, breaks conflicts
  int dh = blockIdx.y;
  int tile = blockIdx.x;
  int f0 = (tile >> 2) * 64, o0 = (tile & 3) * 64;
  const float* src = W + dh * 65536;
  u16* dst = Wt + dh * 65536;
  int tdx = threadIdx.x;
  for (int i = 0; i < 2; ++i) {
    int c = i * 256 + tdx;                  // 0..511 chunks of 8 elems
    int row = c >> 3, cc = (c & 7) * 8;
    float4 v0 = *(const float4*)&src[(f0 + row) * 256 + o0 + cc];
    float4 v1 = *(const float4*)&src[(f0 + row) * 256 + o0 + cc + 4];
    u16 tmp[8] __attribute__((aligned(16)));
    tmp[0] = f2bf(v0.x); tmp[1] = f2bf(v0.y); tmp[2] = f2bf(v0.z); tmp[3] = f2bf(v0.w);
    tmp[4] = f2bf(v1.x); tmp[5] = f2bf(v1.y); tmp[6] = f2bf(v1.z); tmp[7] = f2bf(v1.w);
    *(uint4*)&t[row][cc] = *(uint4*)tmp;
  }
  __syncthreads();
  for (int i = 0; i < 2; ++i) {
    int c = i * 256 + tdx;
    int orow = c >> 3, fc = (c & 7) * 8;
    u16 v[8] __attribute__((aligned(16)));
#pragma unroll
    for (int k = 0; k < 8; ++k) v[k] = t[fc + k][orow];
    *(uint4*)&dst[(o0 + orow) * 256 + f0 + fc] = *(uint4*)v;
  }
}

// ---------------------------------------------------------------------------
// K1b: vsrc[d][f] = sum_o W[d,1,f,o]*a[d,1,o] ; vdst with a[d,1,256+o]. fp32.
__global__ void k_vsd(const float* __restrict__ W, const float* __restrict__ a,
                      float* __restrict__ vsrc, float* __restrict__ vdst) {
  int blk = blockIdx.x;           // 1024 blocks: d = blk>>8, f = blk&255
  int d = blk >> 8, f = blk & 255;
  int o = threadIdx.x;
  int dh = d * 2 + 1;
  float w = W[(dh * 256 + f) * 256 + o];
  float as = a[dh * 512 + o];
  float ad = a[dh * 512 + 256 + o];
  float ps = w * as, pd = w * ad;
  __shared__ float red[2][4];
  for (int off = 32; off; off >>= 1) {
    ps += __shfl_down(ps, off);
    pd += __shfl_down(pd, off);
  }
  int lane = o & 63, w4 = o >> 6;
  if (lane == 0) { red[0][w4] = ps; red[1][w4] = pd; }
  __syncthreads();
  if (o == 0) vsrc[d * 256 + f] = red[0][0] + red[0][1] + red[0][2] + red[0][3];
  if (o == 1) vdst[d * 256 + f] = red[1][0] + red[1][1] + red[1][2] + red[1][3];
}

// ---------------------------------------------------------------------------
// K2: e_src[d][b][n] = x[b,n,:]·vsrc[d]; e_dst likewise. One block per (b,n). fp32.
__global__ void k_edots(const float* __restrict__ x, const float* __restrict__ vsrc,
                        const float* __restrict__ vdst, float* __restrict__ es,
                        float* __restrict__ ed) {
  int row = blockIdx.x;  // b*1024+n
  int f = threadIdx.x;
  float xv = x[(size_t)row * 256 + f];
  float p[8];
#pragma unroll
  for (int d = 0; d < 4; ++d) {
    p[d] = xv * vsrc[d * 256 + f];
    p[4 + d] = xv * vdst[d * 256 + f];
  }
#pragma unroll
  for (int v = 0; v < 8; ++v)
    for (int off = 32; off; off >>= 1) p[v] += __shfl_down(p[v], off);
  __shared__ float red[8][4];
  int lane = f & 63, w4 = f >> 6;
  if (lane == 0) {
    for (int v = 0; v < 8; ++v) red[v][w4] = p[v];
  }
  __syncthreads();
  if (f < 8) {
    float s = red[f][0] + red[f][1] + red[f][2] + red[f][3];
    int d = f & 3;
    int b = row >> 10, n = row & 1023;
    float* dstp = (f < 4) ? es : ed;
    dstp[(d * 8 + b) * 1024 + n] = s;
  }
}

// ---------------------------------------------------------------------------
// K4: pack adjacency into 4-bit masks, 4 per u32.
__global__ void k_mask(const int* __restrict__ AU, const int* __restrict__ AD,
                       const int* __restrict__ AR, const int* __restrict__ AL,
                       u32* __restrict__ mask) {
  int idx = blockIdx.x * 256 + threadIdx.x;  // 262144 u32 total
  int base = idx * 4;
  int4 au = *(const int4*)&AU[base];
  int4 ad = *(const int4*)&AD[base];
  int4 ar = *(const int4*)&AR[base];
  int4 al = *(const int4*)&AL[base];
  u32 m0 = (au.x ? 1u : 0u) | (ad.x ? 2u : 0u) | (ar.x ? 4u : 0u) | (al.x ? 8u : 0u);
  u32 m1 = (au.y ? 1u : 0u) | (ad.y ? 2u : 0u) | (ar.y ? 4u : 0u) | (al.y ? 8u : 0u);
  u32 m2 = (au.z ? 1u : 0u) | (ad.z ? 2u : 0u) | (ar.z ? 4u : 0u) | (al.z ? 8u : 0u);
  u32 m3 = (au.w ? 1u : 0u) | (ad.w ? 2u : 0u) | (ar.w ? 4u : 0u) | (al.w ? 8u : 0u);
  mask[idx] = m0 | (m1 << 8) | (m2 << 16) | (m3 << 24);
}

// ---------------------------------------------------------------------------
// K3: Whst[d][b][o][n] (bf16) = transpose of Xb(bf16) @ (W[d,0]+W[d,1]).
// 128x128 tile, 4 waves (2x2), each wave 4x4 16x16 tiles, K loop h=0,1 x 256.
// Output is j(=n)-contiguous so k_agg B-frags are direct ds_read_b128s.
__global__ __launch_bounds__(256, 2) void k_whsum(const u16* __restrict__ X,
                                                  const u16* __restrict__ Wt,
                                                  u16* __restrict__ Whst) {
  __shared__ u16 lA[128 * 32];
  __shared__ u16 lB[128 * 32];
  int d = blockIdx.z;
  int m0 = blockIdx.y * 128;
  int o0 = blockIdx.x * 128;
  int t = threadIdx.x;
  int lane = t & 63, w = t >> 6;
  int wm = w >> 1, wn = w & 1;
  int r16 = lane & 15, q8 = (lane >> 4) * 8;
  f4 acc[4][4];
  const f4 fz = {0.f, 0.f, 0.f, 0.f};
#pragma unroll
  for (int i = 0; i < 4; ++i)
#pragma unroll
    for (int j = 0; j < 4; ++j) acc[i][j] = fz;

  for (int h = 0; h < 2; ++h) {
    const u16* Bp = Wt + (size_t)(d * 2 + h) * 65536;  // [o][f] 256x256
    for (int k0 = 0; k0 < 256; k0 += 32) {
      uint4 va[2], vb[2];
#pragma unroll
      for (int i = 0; i < 2; ++i) {
        int c = i * 256 + t;                 // 0..511 chunks (16B) of the tile
        int row = c >> 2, ko = (c & 3) * 8;  // 4 chunks per 32-wide row
        va[i] = *(const uint4*)&X[(size_t)(m0 + row) * 256 + k0 + ko];
        vb[i] = *(const uint4*)&Bp[(o0 + row) * 256 + k0 + ko];
      }
      __syncthreads();  // previous compute done reading LDS
#pragma unroll
      for (int i = 0; i < 2; ++i) {
        int c = i * 256 + t;
        *(uint4*)&lA[c * 8] = va[i];
        *(uint4*)&lB[c * 8] = vb[i];
      }
      __syncthreads();
      bf8 af[4], bfr[4];
#pragma unroll
      for (int tm = 0; tm < 4; ++tm)
        af[tm] = *(const bf8*)&lA[(wm * 64 + tm * 16 + r16) * 32 + q8];
#pragma unroll
      for (int tn = 0; tn < 4; ++tn)
        bfr[tn] = *(const bf8*)&lB[(wn * 64 + tn * 16 + r16) * 32 + q8];
#pragma unroll
      for (int tm = 0; tm < 4; ++tm)
#pragma unroll
        for (int tn = 0; tn < 4; ++tn)
          acc[tm][tn] = __builtin_amdgcn_mfma_f32_16x16x32_bf16(
              af[tm], bfr[tn], acc[tm][tn], 0, 0, 0);
    }
  }
  // epilogue: C/D layout col=lane&15, row=(lane>>4)*4+reg  [verified m89/m91]
  // Write transposed bf16: Whst[((d*8+b)*256 + o)*1024 + n], 4 consecutive n
  // per lane -> one 8B store.
  int b = m0 >> 10;           // 1024 % 128 == 0 -> whole tile in one b
  int nb = (m0 & 1023) + wm * 64;
#pragma unroll
  for (int tm = 0; tm < 4; ++tm) {
#pragma unroll
    for (int tn = 0; tn < 4; ++tn) {
      int n0 = nb + tm * 16 + (lane >> 4) * 4;
      int go = o0 + wn * 64 + tn * 16 + r16;
      u16 p[4] __attribute__((aligned(8)));
#pragma unroll
      for (int r = 0; r < 4; ++r) p[r] = f2bf(acc[tm][tn][r]);
      *(uint2*)&Whst[(((size_t)d * 8 + b) * 256 + go) * 1024 + n0] = *(uint2*)p;
    }
  }
}

// ---------------------------------------------------------------------------
// K5: e_total row -> softmax -> alpha (bf16 out). One block per (b,i).
__global__ void k_softmax(const float* __restrict__ es, const float* __restrict__ ed,
                          const u32* __restrict__ maskw, u16* __restrict__ alphab) {
  int blk = blockIdx.x;  // b*1024 + i
  int b = blk >> 10, i = blk & 1023;
  int t = threadIdx.x;
  float e0 = es[(0 * 8 + b) * 1024 + i];
  float e1 = es[(1 * 8 + b) * 1024 + i];
  float e2 = es[(2 * 8 + b) * 1024 + i];
  float e3 = es[(3 * 8 + b) * 1024 + i];
  const unsigned char* mask = (const unsigned char*)maskw;
  float et[4];
  float mx = -__builtin_inff();
#pragma unroll
  for (int jj = 0; jj < 4; ++jj) {
    int j = jj * 256 + t;
    unsigned m = mask[i * 1024 + j];
    float e;
    if (m) {
      int d = 31 - __clz((int)m);  // last direction with A!=0 wins
      float esd = d == 0 ? e0 : d == 1 ? e1 : d == 2 ? e2 : e3;
      float z = esd + ed[(d * 8 + b) * 1024 + j];
      e = z > 0.0f ? z : 0.01f * z;  // leaky_relu(0.01)
    } else {
      e = -__builtin_inff();
    }
    et[jj] = e;
    mx = fmaxf(mx, e);
  }
  __shared__ float red[4];
  __shared__ float red2[4];
  for (int off = 32; off; off >>= 1) mx = fmaxf(mx, __shfl_xor(mx, off));
  if ((t & 63) == 0) red[t >> 6] = mx;
  __syncthreads();
  mx = fmaxf(fmaxf(red[0], red[1]), fmaxf(red[2], red[3]));
  float p[4];
  float s = 0.f;
#pragma unroll
  for (int jj = 0; jj < 4; ++jj) {
    p[jj] = exp2f((et[jj] - mx) * 1.4426950408889634f);  // exp(-inf)=0 for masked
    s += p[jj];
  }
  for (int off = 32; off; off >>= 1) s += __shfl_xor(s, off);
  if ((t & 63) == 0) red2[t >> 6] = s;
  __syncthreads();
  s = red2[0] + red2[1] + red2[2] + red2[3];
  float rs = 1.0f / s;
#pragma unroll
  for (int jj = 0; jj < 4; ++jj) {
    int j = jj * 256 + t;
    alphab[((size_t)b * 1024 + i) * 1024 + j] = f2bf(p[jj] * rs);
  }
}

// ---------------------------------------------------------------------------
// K6: out[b,i,o] += 0.5 * sum_d ((alpha .* M_d) @ Whst[d,b]^T)[i,o]   via MFMA.
// 128i x 128o tile, 4 waves of 64x64, split-K=2 over j, atomicAdd epilogue.
// A-frags (alpha masked per d) built in registers from global (no LDS round
// trip); B (Whst) staged in LDS with 40-halfword row stride (<=2-way banks).
__global__ __launch_bounds__(256, 2) void k_agg(const u16* __restrict__ alphab,
                                                const u32* __restrict__ maskw,
                                                const u16* __restrict__ Whst,
                                                float* __restrict__ out) {
  __shared__ u16 sB[4 * 128 * 40];  // 40960 B
  int o0 = blockIdx.x * 128;
  int i0 = blockIdx.y * 128;
  int bz = blockIdx.z;
  int b = bz >> 1, ks = bz & 1;
  int t = threadIdx.x;
  int lane = t & 63, w = t >> 6;
  int wm = w >> 1, wn = w & 1;
  int r16 = lane & 15, q8 = (lane >> 4) * 8;
  const unsigned char* maskb = (const unsigned char*)maskw;
  f4 acc[4][4];
  const f4 fz = {0.f, 0.f, 0.f, 0.f};
#pragma unroll
  for (int i = 0; i < 4; ++i)
#pragma unroll
    for (int j = 0; j < 4; ++j) acc[i][j] = fz;

  for (int js = 0; js < 16; ++js) {
    int j0 = ks * 512 + js * 32;
    // prefetch B tile (4d x 128o x 32j) into regs
    uint4 vb[8];
#pragma unroll
    for (int it = 0; it < 8; ++it) {
      int c = it * 256 + t;
      int d = c >> 9, rem = c & 511;
      int o = rem >> 2, jc = (rem & 3) * 8;
      vb[it] = *(const uint4*)&Whst[(((size_t)d * 8 + b) * 256 + o0 + o) * 1024 + j0 + jc];
    }
    // raw alpha + mask for this wave's A rows (global, no LDS)
    uint4 ar[4];
    uint2 mr[4];
#pragma unroll
    for (int tm = 0; tm < 4; ++tm) {
      int i = i0 + wm * 64 + tm * 16 + r16;
      ar[tm] = *(const uint4*)&alphab[((size_t)b * 1024 + i) * 1024 + j0 + q8];
      mr[tm] = *(const uint2*)&maskb[(size_t)i * 1024 + j0 + q8];
    }
    __syncthreads();  // prev iter done reading sB
#pragma unroll
    for (int it = 0; it < 8; ++it) {
      int c = it * 256 + t;
      int d = c >> 9, rem = c & 511;
      int o = rem >> 2, jc = (rem & 3) * 8;
      *(uint4*)&sB[(d * 128 + o) * 40 + jc] = vb[it];
    }
    __syncthreads();
    for (int d = 0; d < 4; ++d) {
      union { uint4 u; bf8 h; } bfr[4], af[4];
#pragma unroll
      for (int tn = 0; tn < 4; ++tn)
        bfr[tn].h = *(const bf8*)&sB[(d * 128 + wn * 64 + tn * 16 + r16) * 40 + q8];
#pragma unroll
      for (int tm = 0; tm < 4; ++tm) {
        u32 t0 = (mr[tm].x >> d) & 0x01010101u;
        u32 t1 = (mr[tm].y >> d) & 0x01010101u;
        uint4 f;
        f.x = ar[tm].x & (((t0 & 1u) * 0xFFFFu) | (((t0 >> 8) & 1u) * 0xFFFF0000u));
        f.y = ar[tm].y & ((((t0 >> 16) & 1u) * 0xFFFFu) | ((t0 >> 24) * 0xFFFF0000u));
        f.z = ar[tm].z & (((t1 & 1u) * 0xFFFFu) | (((t1 >> 8) & 1u) * 0xFFFF0000u));
        f.w = ar[tm].w & ((((t1 >> 16) & 1u) * 0xFFFFu) | ((t1 >> 24) * 0xFFFF0000u));
        af[tm].u = f;
      }
#pragma unroll
      for (int tm = 0; tm < 4; ++tm)
#pragma unroll
        for (int tn = 0; tn < 4; ++tn)
          acc[tm][tn] = __builtin_amdgcn_mfma_f32_16x16x32_bf16(
              af[tm].h, bfr[tn].h, acc[tm][tn], 0, 0, 0);
    }
  }
  // epilogue: atomicAdd 0.5*acc into out (split-K partial merge)
#pragma unroll
  for (int tm = 0; tm < 4; ++tm) {
#pragma unroll
    for (int tn = 0; tn < 4; ++tn) {
      int ib = i0 + wm * 64 + tm * 16 + (lane >> 4) * 4;
      int go = o0 + wn * 64 + tn * 16 + r16;
#pragma unroll
      for (int r = 0; r < 4; ++r)
        atomicAdd(&out[((size_t)b * 1024 + ib + r) * 256 + go], 0.5f * acc[tm][tn][r]);
    }
  }
}

// ---------------------------------------------------------------------------
extern "C" void kernel_launch(void* const* d_in, const int* in_sizes, int n_in,
                              void* d_out, int out_size, void* d_ws, size_t ws_size,
                              hipStream_t stream) {
  const float* x = (const float*)d_in[0];
  const int* AU = (const int*)d_in[1];
  const int* AD = (const int*)d_in[2];
  const int* AR = (const int*)d_in[3];
  const int* AL = (const int*)d_in[4];
  const float* W = (const float*)d_in[5];
  const float* a = (const float*)d_in[6];
  float* out = (float*)d_out;

  char* ws = (char*)d_ws;
  // workspace layout (bytes) — total ~37.3 MB (<< 66.3 MB known-safe)
  u16* Wt = (u16*)(ws + 0);               //  1 MB  bf16 (d,h,o,f)
  float* vsrc = (float*)(ws + 1048576);   //  4 KB
  float* vdst = (float*)(ws + 1052672);   //  4 KB
  float* es = (float*)(ws + 1056768);     // 128 KB (d,b,n)
  float* ed = (float*)(ws + 1187840);     // 128 KB
  u32* maskw = (u32*)(ws + 1318912);      //  1 MB  u8 (i,j)
  u16* xb = (u16*)(ws + 2367488);         //  4 MB  bf16 x
  u16* Whst = (u16*)(ws + 6561792);       // 16 MB  bf16 (d,b,o,n)
  u16* alphab = (u16*)(ws + 23339008);    // 16 MB  bf16 (b,i,j)
  if (ws_size < 40116224) return;         // need ~38.3 MB

  hipLaunchKernelGGL(k_zero, dim3(2048), dim3(256), 0, stream, out);
  hipLaunchKernelGGL(k_cvt, dim3(2048), dim3(256), 0, stream, x, xb);
  hipLaunchKernelGGL(k_transpose, dim3(16, 8), dim3(256), 0, stream, W, Wt);
  hipLaunchKernelGGL(k_vsd, dim3(1024), dim3(256), 0, stream, W, a, vsrc, vdst);
  hipLaunchKernelGGL(k_edots, dim3(8192), dim3(256), 0, stream, x, vsrc, vdst, es, ed);
  hipLaunchKernelGGL(k_mask, dim3(1024), dim3(256), 0, stream, AU, AD, AR, AL, maskw);
  hipLaunchKernelGGL(k_whsum, dim3(2, 64, 4), dim3(256), 0, stream, xb, Wt, Whst);
  hipLaunchKernelGGL(k_softmax, dim3(8192), dim3(256), 0, stream, es, ed, maskw, alphab);
  hipLaunchKernelGGL(k_agg, dim3(2, 8, 16), dim3(256), 0, stream, alphab, maskw, Whst, out);
}

// Round 4
// 244.085 us; speedup vs baseline: 2.1943x; 1.0633x over previous
//
#include <hip/hip_runtime.h>

// Problem constants
#define B_ 8
#define N_ 1024
#define F_ 256
#define O_ 256

typedef unsigned short u16;
typedef unsigned int u32;
typedef __attribute__((ext_vector_type(8))) short bf8;   // 8 bf16 (4 VGPRs) MFMA frag
typedef __attribute__((ext_vector_type(4))) float f4;    // 4 fp32 MFMA acc

__device__ __forceinline__ u16 f2bf(float f) {
  union { float f; u32 u; } c; c.f = f;
  u32 u = c.u;
  u32 r = u + 0x7FFFu + ((u >> 16) & 1u);  // RNE
  return (u16)(r >> 16);
}

// ---------------------------------------------------------------------------
// K1a: transpose W (d,h,f,o) fp32 -> Wt (d,h,o,f) bf16, so MFMA B-frags
// read 8 contiguous k(=f) elements from LDS.
__global__ void k_transpose(const float* __restrict__ W, u16* __restrict__ Wt) {
  __shared__ u16 t[64][72];  // pad 64->72 keeps 16B alignment, breaks conflicts
  int dh = blockIdx.y;
  int tile = blockIdx.x;
  int f0 = (tile >> 2) * 64, o0 = (tile & 3) * 64;
  const float* src = W + dh * 65536;
  u16* dst = Wt + dh * 65536;
  int tdx = threadIdx.x;
  for (int i = 0; i < 2; ++i) {
    int c = i * 256 + tdx;                  // 0..511 chunks of 8 elems
    int row = c >> 3, cc = (c & 7) * 8;
    float4 v0 = *(const float4*)&src[(f0 + row) * 256 + o0 + cc];
    float4 v1 = *(const float4*)&src[(f0 + row) * 256 + o0 + cc + 4];
    u16 tmp[8] __attribute__((aligned(16)));
    tmp[0] = f2bf(v0.x); tmp[1] = f2bf(v0.y); tmp[2] = f2bf(v0.z); tmp[3] = f2bf(v0.w);
    tmp[4] = f2bf(v1.x); tmp[5] = f2bf(v1.y); tmp[6] = f2bf(v1.z); tmp[7] = f2bf(v1.w);
    *(uint4*)&t[row][cc] = *(uint4*)tmp;
  }
  __syncthreads();
  for (int i = 0; i < 2; ++i) {
    int c = i * 256 + tdx;
    int orow = c >> 3, fc = (c & 7) * 8;
    u16 v[8] __attribute__((aligned(16)));
#pragma unroll
    for (int k = 0; k < 8; ++k) v[k] = t[fc + k][orow];
    *(uint4*)&dst[(o0 + orow) * 256 + f0 + fc] = *(uint4*)v;
  }
}

// ---------------------------------------------------------------------------
// K1b: vsrc[d][f] = sum_o W[d,1,f,o]*a[d,1,o] ; vdst with a[d,1,256+o]. fp32.
__global__ void k_vsd(const float* __restrict__ W, const float* __restrict__ a,
                      float* __restrict__ vsrc, float* __restrict__ vdst) {
  int blk = blockIdx.x;           // 1024 blocks: d = blk>>8, f = blk&255
  int d = blk >> 8, f = blk & 255;
  int o = threadIdx.x;
  int dh = d * 2 + 1;
  float w = W[(dh * 256 + f) * 256 + o];
  float as = a[dh * 512 + o];
  float ad = a[dh * 512 + 256 + o];
  float ps = w * as, pd = w * ad;
  __shared__ float red[2][4];
  for (int off = 32; off; off >>= 1) {
    ps += __shfl_down(ps, off);
    pd += __shfl_down(pd, off);
  }
  int lane = o & 63, w4 = o >> 6;
  if (lane == 0) { red[0][w4] = ps; red[1][w4] = pd; }
  __syncthreads();
  if (o == 0) vsrc[d * 256 + f] = red[0][0] + red[0][1] + red[0][2] + red[0][3];
  if (o == 1) vdst[d * 256 + f] = red[1][0] + red[1][1] + red[1][2] + red[1][3];
}

// ---------------------------------------------------------------------------
// K2: e_src[d][b][n] = x[b,n,:]·vsrc[d]; e_dst likewise. One block per (b,n).
// Also emits xb = bf16(x) for the MFMA path (x read exactly once).
__global__ void k_edots(const float* __restrict__ x, const float* __restrict__ vsrc,
                        const float* __restrict__ vdst, float* __restrict__ es,
                        float* __restrict__ ed, u16* __restrict__ xb) {
  int row = blockIdx.x;  // b*1024+n
  int f = threadIdx.x;
  float xv = x[(size_t)row * 256 + f];
  xb[(size_t)row * 256 + f] = f2bf(xv);
  float p[8];
#pragma unroll
  for (int d = 0; d < 4; ++d) {
    p[d] = xv * vsrc[d * 256 + f];
    p[4 + d] = xv * vdst[d * 256 + f];
  }
#pragma unroll
  for (int v = 0; v < 8; ++v)
    for (int off = 32; off; off >>= 1) p[v] += __shfl_down(p[v], off);
  __shared__ float red[8][4];
  int lane = f & 63, w4 = f >> 6;
  if (lane == 0) {
    for (int v = 0; v < 8; ++v) red[v][w4] = p[v];
  }
  __syncthreads();
  if (f < 8) {
    float s = red[f][0] + red[f][1] + red[f][2] + red[f][3];
    int d = f & 3;
    int b = row >> 10, n = row & 1023;
    float* dstp = (f < 4) ? es : ed;
    dstp[(d * 8 + b) * 1024 + n] = s;
  }
}

// ---------------------------------------------------------------------------
// K4: pack adjacency into 4-bit masks, 4 per u32.
__global__ void k_mask(const int* __restrict__ AU, const int* __restrict__ AD,
                       const int* __restrict__ AR, const int* __restrict__ AL,
                       u32* __restrict__ mask) {
  int idx = blockIdx.x * 256 + threadIdx.x;  // 262144 u32 total
  int base = idx * 4;
  int4 au = *(const int4*)&AU[base];
  int4 ad = *(const int4*)&AD[base];
  int4 ar = *(const int4*)&AR[base];
  int4 al = *(const int4*)&AL[base];
  u32 m0 = (au.x ? 1u : 0u) | (ad.x ? 2u : 0u) | (ar.x ? 4u : 0u) | (al.x ? 8u : 0u);
  u32 m1 = (au.y ? 1u : 0u) | (ad.y ? 2u : 0u) | (ar.y ? 4u : 0u) | (al.y ? 8u : 0u);
  u32 m2 = (au.z ? 1u : 0u) | (ad.z ? 2u : 0u) | (ar.z ? 4u : 0u) | (al.z ? 8u : 0u);
  u32 m3 = (au.w ? 1u : 0u) | (ad.w ? 2u : 0u) | (ar.w ? 4u : 0u) | (al.w ? 8u : 0u);
  mask[idx] = m0 | (m1 << 8) | (m2 << 16) | (m3 << 24);
}

// ---------------------------------------------------------------------------
// K3: Whst[d][b][o][n] (bf16) = transpose of Xb(bf16) @ (W[d,0]+W[d,1]).
// 128x128 tile, 4 waves (2x2), each wave 4x4 16x16 tiles, K loop h=0,1 x 256.
// Epilogue transposes through LDS so global stores are n-contiguous 16B
// chunks (R3's direct 8B/lane stores at 2KB stride were ~8x write-amplified).
__global__ __launch_bounds__(256, 2) void k_whsum(const u16* __restrict__ X,
                                                  const u16* __restrict__ Wt,
                                                  u16* __restrict__ Whst) {
  __shared__ u16 lA[128 * 32];
  __shared__ u16 lB[128 * 32];
  __shared__ u16 sC[128 * 136];  // [o][n], stride 136 halfwords
  int d = blockIdx.z;
  int m0 = blockIdx.y * 128;
  int o0 = blockIdx.x * 128;
  int t = threadIdx.x;
  int lane = t & 63, w = t >> 6;
  int wm = w >> 1, wn = w & 1;
  int r16 = lane & 15, quad = lane >> 4, q8 = quad * 8;
  f4 acc[4][4];
  const f4 fz = {0.f, 0.f, 0.f, 0.f};
#pragma unroll
  for (int i = 0; i < 4; ++i)
#pragma unroll
    for (int j = 0; j < 4; ++j) acc[i][j] = fz;

  for (int h = 0; h < 2; ++h) {
    const u16* Bp = Wt + (size_t)(d * 2 + h) * 65536;  // [o][f] 256x256
    for (int k0 = 0; k0 < 256; k0 += 32) {
      uint4 va[2], vb[2];
#pragma unroll
      for (int i = 0; i < 2; ++i) {
        int c = i * 256 + t;                 // 0..511 chunks (16B) of the tile
        int row = c >> 2, ko = (c & 3) * 8;  // 4 chunks per 32-wide row
        va[i] = *(const uint4*)&X[(size_t)(m0 + row) * 256 + k0 + ko];
        vb[i] = *(const uint4*)&Bp[(o0 + row) * 256 + k0 + ko];
      }
      __syncthreads();  // previous compute done reading LDS
#pragma unroll
      for (int i = 0; i < 2; ++i) {
        int c = i * 256 + t;
        *(uint4*)&lA[c * 8] = va[i];
        *(uint4*)&lB[c * 8] = vb[i];
      }
      __syncthreads();
      bf8 af[4], bfr[4];
#pragma unroll
      for (int tm = 0; tm < 4; ++tm)
        af[tm] = *(const bf8*)&lA[(wm * 64 + tm * 16 + r16) * 32 + q8];
#pragma unroll
      for (int tn = 0; tn < 4; ++tn)
        bfr[tn] = *(const bf8*)&lB[(wn * 64 + tn * 16 + r16) * 32 + q8];
#pragma unroll
      for (int tm = 0; tm < 4; ++tm)
#pragma unroll
        for (int tn = 0; tn < 4; ++tn)
          acc[tm][tn] = __builtin_amdgcn_mfma_f32_16x16x32_bf16(
              af[tm], bfr[tn], acc[tm][tn], 0, 0, 0);
    }
  }
  // epilogue: C/D layout col=lane&15, row=(lane>>4)*4+reg  [verified m89/m91]
  // Each wave writes its exclusive sC region [o = wn*64.. ][n = wm*64..].
#pragma unroll
  for (int tm = 0; tm < 4; ++tm) {
#pragma unroll
    for (int tn = 0; tn < 4; ++tn) {
      int o = wn * 64 + tn * 16 + r16;
      int n = wm * 64 + tm * 16 + quad * 4;
      u16 p[4] __attribute__((aligned(8)));
#pragma unroll
      for (int r = 0; r < 4; ++r) p[r] = f2bf(acc[tm][tn][r]);
      *(uint2*)&sC[o * 136 + n] = *(uint2*)p;
    }
  }
  __syncthreads();
  int b = m0 >> 10;            // 1024 % 128 == 0 -> whole tile in one b
  int nlo = m0 & 1023;
#pragma unroll
  for (int it = 0; it < 8; ++it) {
    int c = it * 256 + t;      // 2048 uint4 chunks of the 128x128 C-tile
    int o = c >> 4, nc = (c & 15) * 8;
    uint4 v = *(const uint4*)&sC[o * 136 + nc];
    *(uint4*)&Whst[(((size_t)d * 8 + b) * 256 + o0 + o) * 1024 + nlo + nc] = v;
  }
}

// ---------------------------------------------------------------------------
// K5: e_total row -> softmax -> alpha (bf16 out). One block per (b,i).
__global__ void k_softmax(const float* __restrict__ es, const float* __restrict__ ed,
                          const u32* __restrict__ maskw, u16* __restrict__ alphab) {
  int blk = blockIdx.x;  // b*1024 + i
  int b = blk >> 10, i = blk & 1023;
  int t = threadIdx.x;
  float e0 = es[(0 * 8 + b) * 1024 + i];
  float e1 = es[(1 * 8 + b) * 1024 + i];
  float e2 = es[(2 * 8 + b) * 1024 + i];
  float e3 = es[(3 * 8 + b) * 1024 + i];
  const unsigned char* mask = (const unsigned char*)maskw;
  float et[4];
  float mx = -__builtin_inff();
#pragma unroll
  for (int jj = 0; jj < 4; ++jj) {
    int j = jj * 256 + t;
    unsigned m = mask[i * 1024 + j];
    float e;
    if (m) {
      int d = 31 - __clz((int)m);  // last direction with A!=0 wins
      float esd = d == 0 ? e0 : d == 1 ? e1 : d == 2 ? e2 : e3;
      float z = esd + ed[(d * 8 + b) * 1024 + j];
      e = z > 0.0f ? z : 0.01f * z;  // leaky_relu(0.01)
    } else {
      e = -__builtin_inff();
    }
    et[jj] = e;
    mx = fmaxf(mx, e);
  }
  __shared__ float red[4];
  __shared__ float red2[4];
  for (int off = 32; off; off >>= 1) mx = fmaxf(mx, __shfl_xor(mx, off));
  if ((t & 63) == 0) red[t >> 6] = mx;
  __syncthreads();
  mx = fmaxf(fmaxf(red[0], red[1]), fmaxf(red[2], red[3]));
  float p[4];
  float s = 0.f;
#pragma unroll
  for (int jj = 0; jj < 4; ++jj) {
    p[jj] = exp2f((et[jj] - mx) * 1.4426950408889634f);  // exp(-inf)=0 for masked
    s += p[jj];
  }
  for (int off = 32; off; off >>= 1) s += __shfl_xor(s, off);
  if ((t & 63) == 0) red2[t >> 6] = s;
  __syncthreads();
  s = red2[0] + red2[1] + red2[2] + red2[3];
  float rs = 1.0f / s;
#pragma unroll
  for (int jj = 0; jj < 4; ++jj) {
    int j = jj * 256 + t;
    alphab[((size_t)b * 1024 + i) * 1024 + j] = f2bf(p[jj] * rs);
  }
}

// ---------------------------------------------------------------------------
// K6: part[ks][b,i,o] = sum_{j in ks-half} sum_d ((alpha .* M_d) @ Whst[d,b]^T)
// 128i x 64o tile, 4 waves of 64x32, split-K=2 over j -> 512 blocks (>=2/CU).
// B-stage software-pipelined one full iteration ahead; plain coalesced stores
// (no atomics; k_reduce merges the two halves).
__global__ __launch_bounds__(256) void k_agg(const u16* __restrict__ alphab,
                                             const u32* __restrict__ maskw,
                                             const u16* __restrict__ Whst,
                                             float* __restrict__ part) {
  __shared__ u16 sB[256 * 40];  // [d*64+o][j], stride 40 halfwords, 20 KB
  int o0 = blockIdx.x * 64;     // 4 o-tiles
  int i0 = blockIdx.y * 128;    // 8 i-tiles
  int bz = blockIdx.z;          // 16 = b*2 + ks
  int b = bz >> 1, ks = bz & 1;
  int t = threadIdx.x;
  int lane = t & 63, w = t >> 6;
  int wm = w >> 1, wn = w & 1;
  int r16 = lane & 15, quad = lane >> 4, q8 = quad * 8;
  const unsigned char* maskb = (const unsigned char*)maskw;
  f4 acc[4][2];
  const f4 fz = {0.f, 0.f, 0.f, 0.f};
#pragma unroll
  for (int i = 0; i < 4; ++i) { acc[i][0] = fz; acc[i][1] = fz; }

  int jbase = ks * 512;
  uint4 vb[4];
  // preload B tile for js=0
#pragma unroll
  for (int it = 0; it < 4; ++it) {
    int c = it * 256 + t;
    int row = c >> 2, jc = (c & 3) * 8;
    int d = row >> 6, o = row & 63;
    vb[it] = *(const uint4*)&Whst[(((size_t)d * 8 + b) * 256 + o0 + o) * 1024 + jbase + jc];
  }

  for (int js = 0; js < 16; ++js) {
    __syncthreads();  // prev iter done reading sB
#pragma unroll
    for (int it = 0; it < 4; ++it) {
      int c = it * 256 + t;
      int row = c >> 2, jc = (c & 3) * 8;
      *(uint4*)&sB[row * 40 + jc] = vb[it];
    }
    __syncthreads();
    int j0 = jbase + js * 32;
    // A loads for current js (small; consumed shortly, hidden by occupancy)
    uint4 ar[4];
    uint2 mr[4];
#pragma unroll
    for (int tm = 0; tm < 4; ++tm) {
      int i = i0 + wm * 64 + tm * 16 + r16;
      ar[tm] = *(const uint4*)&alphab[((size_t)b * 1024 + i) * 1024 + j0 + q8];
      mr[tm] = *(const uint2*)&maskb[(size_t)i * 1024 + j0 + q8];
    }
    // B prefetch for next js — lands during this step's compute + next barrier
    int jn = jbase + (js < 15 ? js + 1 : 15) * 32;
#pragma unroll
    for (int it = 0; it < 4; ++it) {
      int c = it * 256 + t;
      int row = c >> 2, jc = (c & 3) * 8;
      int d = row >> 6, o = row & 63;
      vb[it] = *(const uint4*)&Whst[(((size_t)d * 8 + b) * 256 + o0 + o) * 1024 + jn + jc];
    }
#pragma unroll
    for (int d = 0; d < 4; ++d) {
      union { uint4 u; bf8 h; } bfr[2], af[4];
#pragma unroll
      for (int tn = 0; tn < 2; ++tn)
        bfr[tn].h = *(const bf8*)&sB[(d * 64 + wn * 32 + tn * 16 + r16) * 40 + q8];
#pragma unroll
      for (int tm = 0; tm < 4; ++tm) {
        u32 t0 = (mr[tm].x >> d) & 0x01010101u;
        u32 t1 = (mr[tm].y >> d) & 0x01010101u;
        uint4 f;
        f.x = ar[tm].x & (((t0 & 1u) * 0xFFFFu) | (((t0 >> 8) & 1u) * 0xFFFF0000u));
        f.y = ar[tm].y & ((((t0 >> 16) & 1u) * 0xFFFFu) | ((t0 >> 24) * 0xFFFF0000u));
        f.z = ar[tm].z & (((t1 & 1u) * 0xFFFFu) | (((t1 >> 8) & 1u) * 0xFFFF0000u));
        f.w = ar[tm].w & ((((t1 >> 16) & 1u) * 0xFFFFu) | ((t1 >> 24) * 0xFFFF0000u));
        af[tm].u = f;
      }
#pragma unroll
      for (int tm = 0; tm < 4; ++tm)
#pragma unroll
        for (int tn = 0; tn < 2; ++tn)
          acc[tm][tn] = __builtin_amdgcn_mfma_f32_16x16x32_bf16(
              af[tm].h, bfr[tn].h, acc[tm][tn], 0, 0, 0);
    }
  }
  // epilogue: coalesced partial stores
  float* P = part + (size_t)ks * 2097152;
#pragma unroll
  for (int tm = 0; tm < 4; ++tm) {
#pragma unroll
    for (int tn = 0; tn < 2; ++tn) {
      int ib = i0 + wm * 64 + tm * 16 + quad * 4;
      int go = o0 + wn * 32 + tn * 16 + r16;
#pragma unroll
      for (int r = 0; r < 4; ++r)
        P[((size_t)b * 1024 + ib + r) * 256 + go] = acc[tm][tn][r];
    }
  }
}

// ---------------------------------------------------------------------------
// K7: out = 0.5 * (P0 + P1)
__global__ void k_reduce(const float* __restrict__ part, float* __restrict__ out) {
  int idx = (blockIdx.x * 256 + threadIdx.x) * 4;
  f4 a = *(const f4*)&part[idx];
  f4 b = *(const f4*)&part[2097152 + idx];
  f4 r = (a + b) * 0.5f;
  *(f4*)&out[idx] = r;
}

// ---------------------------------------------------------------------------
extern "C" void kernel_launch(void* const* d_in, const int* in_sizes, int n_in,
                              void* d_out, int out_size, void* d_ws, size_t ws_size,
                              hipStream_t stream) {
  const float* x = (const float*)d_in[0];
  const int* AU = (const int*)d_in[1];
  const int* AD = (const int*)d_in[2];
  const int* AR = (const int*)d_in[3];
  const int* AL = (const int*)d_in[4];
  const float* W = (const float*)d_in[5];
  const float* a = (const float*)d_in[6];
  float* out = (float*)d_out;

  char* ws = (char*)d_ws;
  // workspace layout (bytes) — total ~54.3 MB (<< 69.5 MB proven available)
  u16* Wt = (u16*)(ws + 0);               //  1 MB  bf16 (d,h,o,f)
  float* vsrc = (float*)(ws + 1048576);   //  4 KB
  float* vdst = (float*)(ws + 1052672);   //  4 KB
  float* es = (float*)(ws + 1056768);     // 128 KB (d,b,n)
  float* ed = (float*)(ws + 1187840);     // 128 KB
  u32* maskw = (u32*)(ws + 1318912);      //  1 MB  u8 (i,j)
  u16* xb = (u16*)(ws + 2367488);         //  4 MB  bf16 x
  u16* Whst = (u16*)(ws + 6561792);       // 16 MB  bf16 (d,b,o,n)
  u16* alphab = (u16*)(ws + 23339008);    // 16 MB  bf16 (b,i,j)
  float* part = (float*)(ws + 40116224);  // 16 MB  fp32 split-K partials
  if (ws_size < 56893440) return;         // need ~54.3 MB

  hipLaunchKernelGGL(k_transpose, dim3(16, 8), dim3(256), 0, stream, W, Wt);
  hipLaunchKernelGGL(k_vsd, dim3(1024), dim3(256), 0, stream, W, a, vsrc, vdst);
  hipLaunchKernelGGL(k_edots, dim3(8192), dim3(256), 0, stream, x, vsrc, vdst, es, ed, xb);
  hipLaunchKernelGGL(k_mask, dim3(1024), dim3(256), 0, stream, AU, AD, AR, AL, maskw);
  hipLaunchKernelGGL(k_whsum, dim3(2, 64, 4), dim3(256), 0, stream, xb, Wt, Whst);
  hipLaunchKernelGGL(k_softmax, dim3(8192), dim3(256), 0, stream, es, ed, maskw, alphab);
  hipLaunchKernelGGL(k_agg, dim3(4, 8, 16), dim3(256), 0, stream, alphab, maskw, Whst, part);
  hipLaunchKernelGGL(k_reduce, dim3(2048), dim3(256), 0, stream, part, out);
}

// Round 5
// 219.174 us; speedup vs baseline: 2.4437x; 1.1137x over previous
//
#include <hip/hip_runtime.h>

// Problem constants
#define B_ 8
#define N_ 1024
#define F_ 256
#define O_ 256

typedef unsigned short u16;
typedef unsigned int u32;
typedef __attribute__((ext_vector_type(8))) short bf8;   // 8 bf16 (4 VGPRs) MFMA frag
typedef __attribute__((ext_vector_type(4))) float f4;    // 4 fp32 MFMA acc

__device__ __forceinline__ u16 f2bf(float f) {
  union { float f; u32 u; } c; c.f = f;
  u32 u = c.u;
  u32 r = u + 0x7FFFu + ((u >> 16) & 1u);  // RNE
  return (u16)(r >> 16);
}

// ---------------------------------------------------------------------------
// K1a: Wt[d][o][f] (bf16) = transpose of (W[d,0]+W[d,1]) — head-sum folded in
// (halves the k_whsum K-loop). fp32 add before convert.
__global__ void k_transpose(const float* __restrict__ W, u16* __restrict__ Wt) {
  __shared__ u16 t[64][72];  // pad 64->72 keeps 16B alignment, breaks conflicts
  int d = blockIdx.y;
  int tile = blockIdx.x;
  int f0 = (tile >> 2) * 64, o0 = (tile & 3) * 64;
  const float* src0 = W + (d * 2 + 0) * 65536;
  const float* src1 = W + (d * 2 + 1) * 65536;
  u16* dst = Wt + d * 65536;
  int tdx = threadIdx.x;
  for (int i = 0; i < 2; ++i) {
    int c = i * 256 + tdx;                  // 0..511 chunks of 8 elems
    int row = c >> 3, cc = (c & 7) * 8;
    int base = (f0 + row) * 256 + o0 + cc;
    float4 a0 = *(const float4*)&src0[base];
    float4 a1 = *(const float4*)&src0[base + 4];
    float4 b0 = *(const float4*)&src1[base];
    float4 b1 = *(const float4*)&src1[base + 4];
    u16 tmp[8] __attribute__((aligned(16)));
    tmp[0] = f2bf(a0.x + b0.x); tmp[1] = f2bf(a0.y + b0.y);
    tmp[2] = f2bf(a0.z + b0.z); tmp[3] = f2bf(a0.w + b0.w);
    tmp[4] = f2bf(a1.x + b1.x); tmp[5] = f2bf(a1.y + b1.y);
    tmp[6] = f2bf(a1.z + b1.z); tmp[7] = f2bf(a1.w + b1.w);
    *(uint4*)&t[row][cc] = *(uint4*)tmp;
  }
  __syncthreads();
  for (int i = 0; i < 2; ++i) {
    int c = i * 256 + tdx;
    int orow = c >> 3, fc = (c & 7) * 8;
    u16 v[8] __attribute__((aligned(16)));
#pragma unroll
    for (int k = 0; k < 8; ++k) v[k] = t[fc + k][orow];
    *(uint4*)&dst[(o0 + orow) * 256 + f0 + fc] = *(uint4*)v;
  }
}

// ---------------------------------------------------------------------------
// K1b: vsrc[d][f] = sum_o W[d,1,f,o]*a[d,1,o] ; vdst with a[d,1,256+o]. fp32.
__global__ void k_vsd(const float* __restrict__ W, const float* __restrict__ a,
                      float* __restrict__ vsrc, float* __restrict__ vdst) {
  int blk = blockIdx.x;           // 1024 blocks: d = blk>>8, f = blk&255
  int d = blk >> 8, f = blk & 255;
  int o = threadIdx.x;
  int dh = d * 2 + 1;
  float w = W[(dh * 256 + f) * 256 + o];
  float as = a[dh * 512 + o];
  float ad = a[dh * 512 + 256 + o];
  float ps = w * as, pd = w * ad;
  __shared__ float red[2][4];
  for (int off = 32; off; off >>= 1) {
    ps += __shfl_down(ps, off);
    pd += __shfl_down(pd, off);
  }
  int lane = o & 63, w4 = o >> 6;
  if (lane == 0) { red[0][w4] = ps; red[1][w4] = pd; }
  __syncthreads();
  if (o == 0) vsrc[d * 256 + f] = red[0][0] + red[0][1] + red[0][2] + red[0][3];
  if (o == 1) vdst[d * 256 + f] = red[1][0] + red[1][1] + red[1][2] + red[1][3];
}

// ---------------------------------------------------------------------------
// K2: e_src[d][b][n] = x[b,n,:]·vsrc[d]; e_dst likewise. One block per (b,n).
// Also emits xb = bf16(x) for the MFMA path (x read exactly once).
__global__ void k_edots(const float* __restrict__ x, const float* __restrict__ vsrc,
                        const float* __restrict__ vdst, float* __restrict__ es,
                        float* __restrict__ ed, u16* __restrict__ xb) {
  int row = blockIdx.x;  // b*1024+n
  int f = threadIdx.x;
  float xv = x[(size_t)row * 256 + f];
  xb[(size_t)row * 256 + f] = f2bf(xv);
  float p[8];
#pragma unroll
  for (int d = 0; d < 4; ++d) {
    p[d] = xv * vsrc[d * 256 + f];
    p[4 + d] = xv * vdst[d * 256 + f];
  }
#pragma unroll
  for (int v = 0; v < 8; ++v)
    for (int off = 32; off; off >>= 1) p[v] += __shfl_down(p[v], off);
  __shared__ float red[8][4];
  int lane = f & 63, w4 = f >> 6;
  if (lane == 0) {
    for (int v = 0; v < 8; ++v) red[v][w4] = p[v];
  }
  __syncthreads();
  if (f < 8) {
    float s = red[f][0] + red[f][1] + red[f][2] + red[f][3];
    int d = f & 3;
    int b = row >> 10, n = row & 1023;
    float* dstp = (f < 4) ? es : ed;
    dstp[(d * 8 + b) * 1024 + n] = s;
  }
}

// ---------------------------------------------------------------------------
// K4: pack adjacency into 4-bit byte masks (for softmax) AND per-direction
// halfword masks mask_h[d][i][j] in {0,0xFFFF} (for k_agg's 1-AND masking).
// Each thread handles 8 consecutive j.
__global__ void k_mask(const int* __restrict__ AU, const int* __restrict__ AD,
                       const int* __restrict__ AR, const int* __restrict__ AL,
                       u32* __restrict__ mask, u16* __restrict__ mask_h) {
  int idx = blockIdx.x * 256 + threadIdx.x;  // 131072 total, 8 j each
  int base = idx * 8;
  int4 au0 = *(const int4*)&AU[base], au1 = *(const int4*)&AU[base + 4];
  int4 ad0 = *(const int4*)&AD[base], ad1 = *(const int4*)&AD[base + 4];
  int4 ar0 = *(const int4*)&AR[base], ar1 = *(const int4*)&AR[base + 4];
  int4 al0 = *(const int4*)&AL[base], al1 = *(const int4*)&AL[base + 4];
  int u[8] = {au0.x, au0.y, au0.z, au0.w, au1.x, au1.y, au1.z, au1.w};
  int dn[8] = {ad0.x, ad0.y, ad0.z, ad0.w, ad1.x, ad1.y, ad1.z, ad1.w};
  int rr[8] = {ar0.x, ar0.y, ar0.z, ar0.w, ar1.x, ar1.y, ar1.z, ar1.w};
  int ll[8] = {al0.x, al0.y, al0.z, al0.w, al1.x, al1.y, al1.z, al1.w};
  u32 m[8];
#pragma unroll
  for (int k = 0; k < 8; ++k)
    m[k] = (u[k] ? 1u : 0u) | (dn[k] ? 2u : 0u) | (rr[k] ? 4u : 0u) | (ll[k] ? 8u : 0u);
  mask[idx * 2] = m[0] | (m[1] << 8) | (m[2] << 16) | (m[3] << 24);
  mask[idx * 2 + 1] = m[4] | (m[5] << 8) | (m[6] << 16) | (m[7] << 24);
#pragma unroll
  for (int d = 0; d < 4; ++d) {
    u16 h[8] __attribute__((aligned(16)));
#pragma unroll
    for (int k = 0; k < 8; ++k) h[k] = ((m[k] >> d) & 1u) ? 0xFFFFu : 0u;
    *(uint4*)&mask_h[(size_t)d * 1048576 + base] = *(uint4*)h;
  }
}

// ---------------------------------------------------------------------------
// K3: Whst[d][b][o][n] (bf16) = transpose of Xb(bf16) @ Wtsum[d].
// 128x128 tile, 4 waves (2x2), each wave 4x4 16x16 tiles, K=256 (heads
// pre-summed in k_transpose). Epilogue transposes through LDS so global
// stores are n-contiguous 16B chunks.
__global__ __launch_bounds__(256, 2) void k_whsum(const u16* __restrict__ X,
                                                  const u16* __restrict__ Wt,
                                                  u16* __restrict__ Whst) {
  __shared__ u16 lA[128 * 32];
  __shared__ u16 lB[128 * 32];
  __shared__ u16 sC[128 * 136];  // [o][n], stride 136 halfwords
  int d = blockIdx.z;
  int m0 = blockIdx.y * 128;
  int o0 = blockIdx.x * 128;
  int t = threadIdx.x;
  int lane = t & 63, w = t >> 6;
  int wm = w >> 1, wn = w & 1;
  int r16 = lane & 15, quad = lane >> 4, q8 = quad * 8;
  f4 acc[4][4];
  const f4 fz = {0.f, 0.f, 0.f, 0.f};
#pragma unroll
  for (int i = 0; i < 4; ++i)
#pragma unroll
    for (int j = 0; j < 4; ++j) acc[i][j] = fz;

  const u16* Bp = Wt + d * 65536;  // [o][f] 256x256
  for (int k0 = 0; k0 < 256; k0 += 32) {
    uint4 va[2], vb[2];
#pragma unroll
    for (int i = 0; i < 2; ++i) {
      int c = i * 256 + t;                 // 0..511 chunks (16B) of the tile
      int row = c >> 2, ko = (c & 3) * 8;  // 4 chunks per 32-wide row
      va[i] = *(const uint4*)&X[(size_t)(m0 + row) * 256 + k0 + ko];
      vb[i] = *(const uint4*)&Bp[(o0 + row) * 256 + k0 + ko];
    }
    __syncthreads();  // previous compute done reading LDS
#pragma unroll
    for (int i = 0; i < 2; ++i) {
      int c = i * 256 + t;
      *(uint4*)&lA[c * 8] = va[i];
      *(uint4*)&lB[c * 8] = vb[i];
    }
    __syncthreads();
    bf8 af[4], bfr[4];
#pragma unroll
    for (int tm = 0; tm < 4; ++tm)
      af[tm] = *(const bf8*)&lA[(wm * 64 + tm * 16 + r16) * 32 + q8];
#pragma unroll
    for (int tn = 0; tn < 4; ++tn)
      bfr[tn] = *(const bf8*)&lB[(wn * 64 + tn * 16 + r16) * 32 + q8];
#pragma unroll
    for (int tm = 0; tm < 4; ++tm)
#pragma unroll
      for (int tn = 0; tn < 4; ++tn)
        acc[tm][tn] = __builtin_amdgcn_mfma_f32_16x16x32_bf16(
            af[tm], bfr[tn], acc[tm][tn], 0, 0, 0);
  }
  // epilogue: C/D layout col=lane&15, row=(lane>>4)*4+reg  [verified m89/m91]
#pragma unroll
  for (int tm = 0; tm < 4; ++tm) {
#pragma unroll
    for (int tn = 0; tn < 4; ++tn) {
      int o = wn * 64 + tn * 16 + r16;
      int n = wm * 64 + tm * 16 + quad * 4;
      u16 p[4] __attribute__((aligned(8)));
#pragma unroll
      for (int r = 0; r < 4; ++r) p[r] = f2bf(acc[tm][tn][r]);
      *(uint2*)&sC[o * 136 + n] = *(uint2*)p;
    }
  }
  __syncthreads();
  int b = m0 >> 10;            // 1024 % 128 == 0 -> whole tile in one b
  int nlo = m0 & 1023;
#pragma unroll
  for (int it = 0; it < 8; ++it) {
    int c = it * 256 + t;      // 2048 uint4 chunks of the 128x128 C-tile
    int o = c >> 4, nc = (c & 15) * 8;
    uint4 v = *(const uint4*)&sC[o * 136 + nc];
    *(uint4*)&Whst[(((size_t)d * 8 + b) * 256 + o0 + o) * 1024 + nlo + nc] = v;
  }
}

// ---------------------------------------------------------------------------
// K5: e_total row -> softmax -> alpha (bf16 out). One block per (b,i).
__global__ void k_softmax(const float* __restrict__ es, const float* __restrict__ ed,
                          const u32* __restrict__ maskw, u16* __restrict__ alphab) {
  int blk = blockIdx.x;  // b*1024 + i
  int b = blk >> 10, i = blk & 1023;
  int t = threadIdx.x;
  float e0 = es[(0 * 8 + b) * 1024 + i];
  float e1 = es[(1 * 8 + b) * 1024 + i];
  float e2 = es[(2 * 8 + b) * 1024 + i];
  float e3 = es[(3 * 8 + b) * 1024 + i];
  const unsigned char* mask = (const unsigned char*)maskw;
  float et[4];
  float mx = -__builtin_inff();
#pragma unroll
  for (int jj = 0; jj < 4; ++jj) {
    int j = jj * 256 + t;
    unsigned m = mask[i * 1024 + j];
    float e;
    if (m) {
      int d = 31 - __clz((int)m);  // last direction with A!=0 wins
      float esd = d == 0 ? e0 : d == 1 ? e1 : d == 2 ? e2 : e3;
      float z = esd + ed[(d * 8 + b) * 1024 + j];
      e = z > 0.0f ? z : 0.01f * z;  // leaky_relu(0.01)
    } else {
      e = -__builtin_inff();
    }
    et[jj] = e;
    mx = fmaxf(mx, e);
  }
  __shared__ float red[4];
  __shared__ float red2[4];
  for (int off = 32; off; off >>= 1) mx = fmaxf(mx, __shfl_xor(mx, off));
  if ((t & 63) == 0) red[t >> 6] = mx;
  __syncthreads();
  mx = fmaxf(fmaxf(red[0], red[1]), fmaxf(red[2], red[3]));
  float p[4];
  float s = 0.f;
#pragma unroll
  for (int jj = 0; jj < 4; ++jj) {
    p[jj] = exp2f((et[jj] - mx) * 1.4426950408889634f);  // exp(-inf)=0 for masked
    s += p[jj];
  }
  for (int off = 32; off; off >>= 1) s += __shfl_xor(s, off);
  if ((t & 63) == 0) red2[t >> 6] = s;
  __syncthreads();
  s = red2[0] + red2[1] + red2[2] + red2[3];
  float rs = 1.0f / s;
#pragma unroll
  for (int jj = 0; jj < 4; ++jj) {
    int j = jj * 256 + t;
    alphab[((size_t)b * 1024 + i) * 1024 + j] = f2bf(p[jj] * rs);
  }
}

// ---------------------------------------------------------------------------
// K6: part[ks][b,i,o] (bf16) = sum_{j in ks-quarter} sum_d (alpha&mask_h[d]) @ Whst[d,b]^T
// NO LDS, NO barriers: wave-private 64i x 64o tiles, A/B frags loaded straight
// from global (both j-contiguous). Masking = 4 ANDs per (tm,d) via mask_h.
// Grid (2,8,32) = 512 blocks; waves in a block share B (wo) / A (wi) via L1/L2.
__global__ __launch_bounds__(256) void k_agg(const u16* __restrict__ alphab,
                                             const u16* __restrict__ mask_h,
                                             const u16* __restrict__ Whst,
                                             u16* __restrict__ part) {
  int o0 = blockIdx.x * 128;   // 2
  int i0 = blockIdx.y * 128;   // 8
  int z = blockIdx.z;          // 32
  int b = z >> 2, ks = z & 3;
  int t = threadIdx.x, lane = t & 63, w = t >> 6;
  int wi = w >> 1, wo = w & 1;
  int r16 = lane & 15, quad = lane >> 4;
  int ib = i0 + wi * 64, ob = o0 + wo * 64;
  f4 acc[4][4];
  const f4 fz = {0.f, 0.f, 0.f, 0.f};
#pragma unroll
  for (int i = 0; i < 4; ++i)
#pragma unroll
    for (int j = 0; j < 4; ++j) acc[i][j] = fz;

  for (int js = 0; js < 8; ++js) {
    int j0 = ks * 256 + js * 32 + quad * 8;
    uint4 ar[4];
#pragma unroll
    for (int tm = 0; tm < 4; ++tm)
      ar[tm] = *(const uint4*)&alphab[((size_t)b * 1024 + ib + tm * 16 + r16) * 1024 + j0];
#pragma unroll
    for (int d = 0; d < 4; ++d) {
      union { uint4 u; bf8 h; } bfr[4], af[4];
#pragma unroll
      for (int tn = 0; tn < 4; ++tn)
        bfr[tn].u = *(const uint4*)&Whst[(((size_t)d * 8 + b) * 256 + ob + tn * 16 + r16) * 1024 + j0];
#pragma unroll
      for (int tm = 0; tm < 4; ++tm) {
        uint4 mh = *(const uint4*)&mask_h[(size_t)d * 1048576 + (ib + tm * 16 + r16) * 1024 + j0];
        af[tm].u.x = ar[tm].x & mh.x;
        af[tm].u.y = ar[tm].y & mh.y;
        af[tm].u.z = ar[tm].z & mh.z;
        af[tm].u.w = ar[tm].w & mh.w;
      }
#pragma unroll
      for (int tm = 0; tm < 4; ++tm)
#pragma unroll
        for (int tn = 0; tn < 4; ++tn)
          acc[tm][tn] = __builtin_amdgcn_mfma_f32_16x16x32_bf16(
              af[tm].h, bfr[tn].h, acc[tm][tn], 0, 0, 0);
    }
  }
  // epilogue: bf16 partials, [ks][b][i][o]
  u16* P = part + (size_t)ks * 2097152;
#pragma unroll
  for (int tm = 0; tm < 4; ++tm) {
#pragma unroll
    for (int tn = 0; tn < 4; ++tn) {
      int irow = ib + tm * 16 + quad * 4;
      int go = ob + tn * 16 + r16;
#pragma unroll
      for (int r = 0; r < 4; ++r)
        P[((size_t)b * 1024 + irow + r) * 256 + go] = f2bf(acc[tm][tn][r]);
    }
  }
}

// ---------------------------------------------------------------------------
// K7: out = 0.5 * sum_ks part[ks]  (bf16 -> fp32)
__global__ void k_reduce(const u16* __restrict__ part, float* __restrict__ out) {
  int idx = (blockIdx.x * 256 + threadIdx.x) * 8;  // 1024 blocks cover 2M elems
  float s[8];
#pragma unroll
  for (int k = 0; k < 8; ++k) s[k] = 0.f;
#pragma unroll
  for (int ks = 0; ks < 4; ++ks) {
    uint4 v = *(const uint4*)&part[(size_t)ks * 2097152 + idx];
    u32 ww[4] = {v.x, v.y, v.z, v.w};
#pragma unroll
    for (int k = 0; k < 4; ++k) {
      union { u32 i; float f; } lo, hi;
      lo.i = (ww[k] & 0xFFFFu) << 16;
      hi.i = ww[k] & 0xFFFF0000u;
      s[k * 2] += lo.f;
      s[k * 2 + 1] += hi.f;
    }
  }
  float4 o0 = {0.5f * s[0], 0.5f * s[1], 0.5f * s[2], 0.5f * s[3]};
  float4 o1 = {0.5f * s[4], 0.5f * s[5], 0.5f * s[6], 0.5f * s[7]};
  *(float4*)&out[idx] = o0;
  *(float4*)&out[idx + 4] = o1;
}

// ---------------------------------------------------------------------------
extern "C" void kernel_launch(void* const* d_in, const int* in_sizes, int n_in,
                              void* d_out, int out_size, void* d_ws, size_t ws_size,
                              hipStream_t stream) {
  const float* x = (const float*)d_in[0];
  const int* AU = (const int*)d_in[1];
  const int* AD = (const int*)d_in[2];
  const int* AR = (const int*)d_in[3];
  const int* AL = (const int*)d_in[4];
  const float* W = (const float*)d_in[5];
  const float* a = (const float*)d_in[6];
  float* out = (float*)d_out;

  char* ws = (char*)d_ws;
  // workspace layout (bytes) — total 64.76 MB <= 69.48 MB proven available
  u16* Wt = (u16*)(ws + 0);               // 512 KB  bf16 (d,o,f), heads pre-summed
  float* vsrc = (float*)(ws + 524288);    //   4 KB
  float* vdst = (float*)(ws + 528384);    //   4 KB
  float* es = (float*)(ws + 532480);      // 128 KB (d,b,n)
  float* ed = (float*)(ws + 663552);      // 128 KB
  u32* maskw = (u32*)(ws + 794624);       //   1 MB  u8 4-bit masks (i,j)
  u16* mask_h = (u16*)(ws + 1843200);     //   8 MB  u16 0/0xFFFF (d,i,j)
  u16* xb = (u16*)(ws + 10231808);        //   4 MB  bf16 x
  u16* Whst = (u16*)(ws + 14426112);      //  16 MB  bf16 (d,b,o,n)
  u16* alphab = (u16*)(ws + 31203328);    //  16 MB  bf16 (b,i,j)
  u16* part = (u16*)(ws + 47980544);      //  16 MB  bf16 split-K partials
  if (ws_size < 64757760) return;

  hipLaunchKernelGGL(k_transpose, dim3(16, 4), dim3(256), 0, stream, W, Wt);
  hipLaunchKernelGGL(k_vsd, dim3(1024), dim3(256), 0, stream, W, a, vsrc, vdst);
  hipLaunchKernelGGL(k_edots, dim3(8192), dim3(256), 0, stream, x, vsrc, vdst, es, ed, xb);
  hipLaunchKernelGGL(k_mask, dim3(512), dim3(256), 0, stream, AU, AD, AR, AL, maskw, mask_h);
  hipLaunchKernelGGL(k_whsum, dim3(2, 64, 4), dim3(256), 0, stream, xb, Wt, Whst);
  hipLaunchKernelGGL(k_softmax, dim3(8192), dim3(256), 0, stream, es, ed, maskw, alphab);
  hipLaunchKernelGGL(k_agg, dim3(2, 8, 32), dim3(256), 0, stream, alphab, mask_h, Whst, part);
  hipLaunchKernelGGL(k_reduce, dim3(1024), dim3(256), 0, stream, part, out);
}

// Round 6
// 206.795 us; speedup vs baseline: 2.5899x; 1.0599x over previous
//
#include <hip/hip_runtime.h>

// Problem constants
#define B_ 8
#define N_ 1024
#define F_ 256
#define O_ 256

typedef unsigned short u16;
typedef unsigned int u32;
typedef __attribute__((ext_vector_type(8))) short bf8;   // 8 bf16 (4 VGPRs) MFMA frag
typedef __attribute__((ext_vector_type(4))) float f4;    // 4 fp32 MFMA acc

__device__ __forceinline__ u16 f2bf(float f) {
  union { float f; u32 u; } c; c.f = f;
  u32 u = c.u;
  u32 r = u + 0x7FFFu + ((u >> 16) & 1u);  // RNE
  return (u16)(r >> 16);
}
__device__ __forceinline__ float bf2f(u16 u) {
  union { u32 i; float f; } c; c.i = ((u32)u) << 16; return c.f;
}

// byte-dup halfword-mask expansion: e bytes are 0x00/0xFF per j; W = halfword
// masks for j-pairs. v_perm if available, arithmetic fallback otherwise.
#if defined(__has_builtin)
#if __has_builtin(__builtin_amdgcn_perm)
#define HAVE_PERM 1
#endif
#endif
__device__ __forceinline__ u32 dup01(u32 e) {  // bytes (b0,b0,b1,b1)
#ifdef HAVE_PERM
  return __builtin_amdgcn_perm(e, e, 0x01010000u);
#else
  return (e & 0xFFu) * 0x0101u + (e & 0xFF00u) * 0x010100u;
#endif
}
__device__ __forceinline__ u32 dup23(u32 e) {  // bytes (b2,b2,b3,b3)
#ifdef HAVE_PERM
  return __builtin_amdgcn_perm(e, e, 0x03030202u);
#else
  return ((e >> 16) & 0xFFu) * 0x0101u + ((e >> 16) & 0xFF00u) * 0x010100u;
#endif
}

// ---------------------------------------------------------------------------
// K1a: Wt[d][o][f] (bf16) = transpose of (W[d,0]+W[d,1]) — head-sum folded in.
__global__ void k_transpose(const float* __restrict__ W, u16* __restrict__ Wt) {
  __shared__ u16 t[64][72];
  int d = blockIdx.y;
  int tile = blockIdx.x;
  int f0 = (tile >> 2) * 64, o0 = (tile & 3) * 64;
  const float* src0 = W + (d * 2 + 0) * 65536;
  const float* src1 = W + (d * 2 + 1) * 65536;
  u16* dst = Wt + d * 65536;
  int tdx = threadIdx.x;
  for (int i = 0; i < 2; ++i) {
    int c = i * 256 + tdx;
    int row = c >> 3, cc = (c & 7) * 8;
    int base = (f0 + row) * 256 + o0 + cc;
    float4 a0 = *(const float4*)&src0[base];
    float4 a1 = *(const float4*)&src0[base + 4];
    float4 b0 = *(const float4*)&src1[base];
    float4 b1 = *(const float4*)&src1[base + 4];
    u16 tmp[8] __attribute__((aligned(16)));
    tmp[0] = f2bf(a0.x + b0.x); tmp[1] = f2bf(a0.y + b0.y);
    tmp[2] = f2bf(a0.z + b0.z); tmp[3] = f2bf(a0.w + b0.w);
    tmp[4] = f2bf(a1.x + b1.x); tmp[5] = f2bf(a1.y + b1.y);
    tmp[6] = f2bf(a1.z + b1.z); tmp[7] = f2bf(a1.w + b1.w);
    *(uint4*)&t[row][cc] = *(uint4*)tmp;
  }
  __syncthreads();
  for (int i = 0; i < 2; ++i) {
    int c = i * 256 + tdx;
    int orow = c >> 3, fc = (c & 7) * 8;
    u16 v[8] __attribute__((aligned(16)));
#pragma unroll
    for (int k = 0; k < 8; ++k) v[k] = t[fc + k][orow];
    *(uint4*)&dst[(o0 + orow) * 256 + f0 + fc] = *(uint4*)v;
  }
}

// ---------------------------------------------------------------------------
// K1b: vsrc[d][f] = sum_o W[d,1,f,o]*a[d,1,o] ; vdst with a[d,1,256+o].
__global__ void k_vsd(const float* __restrict__ W, const float* __restrict__ a,
                      float* __restrict__ vsrc, float* __restrict__ vdst) {
  int blk = blockIdx.x;
  int d = blk >> 8, f = blk & 255;
  int o = threadIdx.x;
  int dh = d * 2 + 1;
  float w = W[(dh * 256 + f) * 256 + o];
  float as = a[dh * 512 + o];
  float ad = a[dh * 512 + 256 + o];
  float ps = w * as, pd = w * ad;
  __shared__ float red[2][4];
  for (int off = 32; off; off >>= 1) {
    ps += __shfl_down(ps, off);
    pd += __shfl_down(pd, off);
  }
  int lane = o & 63, w4 = o >> 6;
  if (lane == 0) { red[0][w4] = ps; red[1][w4] = pd; }
  __syncthreads();
  if (o == 0) vsrc[d * 256 + f] = red[0][0] + red[0][1] + red[0][2] + red[0][3];
  if (o == 1) vdst[d * 256 + f] = red[1][0] + red[1][1] + red[1][2] + red[1][3];
}

// ---------------------------------------------------------------------------
// K2: e_src/e_dst dots + xb = bf16(x). One block per (b,n).
__global__ void k_edots(const float* __restrict__ x, const float* __restrict__ vsrc,
                        const float* __restrict__ vdst, float* __restrict__ es,
                        float* __restrict__ ed, u16* __restrict__ xb) {
  int row = blockIdx.x;
  int f = threadIdx.x;
  float xv = x[(size_t)row * 256 + f];
  xb[(size_t)row * 256 + f] = f2bf(xv);
  float p[8];
#pragma unroll
  for (int d = 0; d < 4; ++d) {
    p[d] = xv * vsrc[d * 256 + f];
    p[4 + d] = xv * vdst[d * 256 + f];
  }
#pragma unroll
  for (int v = 0; v < 8; ++v)
    for (int off = 32; off; off >>= 1) p[v] += __shfl_down(p[v], off);
  __shared__ float red[8][4];
  int lane = f & 63, w4 = f >> 6;
  if (lane == 0) {
    for (int v = 0; v < 8; ++v) red[v][w4] = p[v];
  }
  __syncthreads();
  if (f < 8) {
    float s = red[f][0] + red[f][1] + red[f][2] + red[f][3];
    int d = f & 3;
    int b = row >> 10, n = row & 1023;
    float* dstp = (f < 4) ? es : ed;
    dstp[(d * 8 + b) * 1024 + n] = s;
  }
}

// ---------------------------------------------------------------------------
// K4: nibble masks (4 bits per (i,j), one byte each) in row-major (nibR, for
// softmax) and frag order (nibF, for k_agg).
__global__ void k_mask(const int* __restrict__ AU, const int* __restrict__ AD,
                       const int* __restrict__ AR, const int* __restrict__ AL,
                       unsigned char* __restrict__ nibR, unsigned char* __restrict__ nibF) {
  int idx = blockIdx.x * 256 + threadIdx.x;  // 131072: i*128 + j/8
  int i = idx >> 7;
  int jb = (idx & 127) * 8;
  int base = i * 1024 + jb;
  int4 au0 = *(const int4*)&AU[base], au1 = *(const int4*)&AU[base + 4];
  int4 ad0 = *(const int4*)&AD[base], ad1 = *(const int4*)&AD[base + 4];
  int4 ar0 = *(const int4*)&AR[base], ar1 = *(const int4*)&AR[base + 4];
  int4 al0 = *(const int4*)&AL[base], al1 = *(const int4*)&AL[base + 4];
  int u[8] = {au0.x, au0.y, au0.z, au0.w, au1.x, au1.y, au1.z, au1.w};
  int dn[8] = {ad0.x, ad0.y, ad0.z, ad0.w, ad1.x, ad1.y, ad1.z, ad1.w};
  int rr[8] = {ar0.x, ar0.y, ar0.z, ar0.w, ar1.x, ar1.y, ar1.z, ar1.w};
  int ll[8] = {al0.x, al0.y, al0.z, al0.w, al1.x, al1.y, al1.z, al1.w};
  unsigned char m[8] __attribute__((aligned(8)));
#pragma unroll
  for (int k = 0; k < 8; ++k)
    m[k] = (unsigned char)((u[k] ? 1u : 0u) | (dn[k] ? 2u : 0u) | (rr[k] ? 4u : 0u) | (ll[k] ? 8u : 0u));
  *(uint2*)&nibR[base] = *(uint2*)m;
  int it = i >> 4, jw = jb >> 5;
  int lane = ((jb >> 3) & 3) * 16 + (i & 15);
  *(uint2*)&nibF[((it * 32 + jw) * 64 + lane) * 8] = *(uint2*)m;
}

// ---------------------------------------------------------------------------
// K3: WhstF = frag-ordered bf16 of (Xb @ Wtsum[d])^T.
// WhstF[d][b][ot16][jw32][lane64][8j]: frag loads in k_agg are lane-contiguous.
__global__ __launch_bounds__(256, 2) void k_whsum(const u16* __restrict__ X,
                                                  const u16* __restrict__ Wt,
                                                  u16* __restrict__ WhstF) {
  __shared__ u16 lA[128 * 32];
  __shared__ u16 lB[128 * 32];
  __shared__ u16 sC[128 * 136];
  int d = blockIdx.z;
  int m0 = blockIdx.y * 128;
  int o0 = blockIdx.x * 128;
  int t = threadIdx.x;
  int lane = t & 63, w = t >> 6;
  int wm = w >> 1, wn = w & 1;
  int r16 = lane & 15, quad = lane >> 4, q8 = quad * 8;
  f4 acc[4][4];
  const f4 fz = {0.f, 0.f, 0.f, 0.f};
#pragma unroll
  for (int i = 0; i < 4; ++i)
#pragma unroll
    for (int j = 0; j < 4; ++j) acc[i][j] = fz;

  const u16* Bp = Wt + d * 65536;
  for (int k0 = 0; k0 < 256; k0 += 32) {
    uint4 va[2], vb[2];
#pragma unroll
    for (int i = 0; i < 2; ++i) {
      int c = i * 256 + t;
      int row = c >> 2, ko = (c & 3) * 8;
      va[i] = *(const uint4*)&X[(size_t)(m0 + row) * 256 + k0 + ko];
      vb[i] = *(const uint4*)&Bp[(o0 + row) * 256 + k0 + ko];
    }
    __syncthreads();
#pragma unroll
    for (int i = 0; i < 2; ++i) {
      int c = i * 256 + t;
      *(uint4*)&lA[c * 8] = va[i];
      *(uint4*)&lB[c * 8] = vb[i];
    }
    __syncthreads();
    bf8 af[4], bfr[4];
#pragma unroll
    for (int tm = 0; tm < 4; ++tm)
      af[tm] = *(const bf8*)&lA[(wm * 64 + tm * 16 + r16) * 32 + q8];
#pragma unroll
    for (int tn = 0; tn < 4; ++tn)
      bfr[tn] = *(const bf8*)&lB[(wn * 64 + tn * 16 + r16) * 32 + q8];
#pragma unroll
    for (int tm = 0; tm < 4; ++tm)
#pragma unroll
      for (int tn = 0; tn < 4; ++tn)
        acc[tm][tn] = __builtin_amdgcn_mfma_f32_16x16x32_bf16(
            af[tm], bfr[tn], acc[tm][tn], 0, 0, 0);
  }
  // stage C tile [o][n] in LDS
#pragma unroll
  for (int tm = 0; tm < 4; ++tm) {
#pragma unroll
    for (int tn = 0; tn < 4; ++tn) {
      int o = wn * 64 + tn * 16 + r16;
      int n = wm * 64 + tm * 16 + quad * 4;
      u16 p[4] __attribute__((aligned(8)));
#pragma unroll
      for (int r = 0; r < 4; ++r) p[r] = f2bf(acc[tm][tn][r]);
      *(uint2*)&sC[o * 136 + n] = *(uint2*)p;
    }
  }
  __syncthreads();
  int b = m0 >> 10;
  int nlo = m0 & 1023;
  int dbbase = d * 8 + b;
  int otg0 = o0 >> 4, jwg0 = nlo >> 5;
#pragma unroll
  for (int cc = 0; cc < 8; ++cc) {
    int c = cc * 256 + t;
    int p = c >> 6, l = c & 63;
    int ot_l = p >> 2, jw_l = p & 3;
    int o_l = ot_l * 16 + (l & 15);
    int j_l = jw_l * 32 + (l >> 4) * 8;
    uint4 v = *(const uint4*)&sC[o_l * 136 + j_l];
    int off = (((dbbase * 16 + otg0 + ot_l) * 32 + jwg0 + jw_l) * 64 + l) * 8;
    *(uint4*)&WhstF[off] = v;
  }
}

// ---------------------------------------------------------------------------
// K5: softmax over e_total rows -> alphaF (frag-ordered bf16).
// Block = (b, itile16): 4 waves x 4 rows each; LDS transpose for frag write.
__global__ void k_softmax(const float* __restrict__ es, const float* __restrict__ ed,
                          const unsigned char* __restrict__ nibR, u16* __restrict__ alphaF) {
  __shared__ u16 sAl[16][1032];
  __shared__ float srs[16];
  int it = blockIdx.x, b = blockIdx.y;
  int t = threadIdx.x, lane = t & 63, w = t >> 6;
  const float NINF = -__builtin_inff();
  for (int rr = 0; rr < 4; ++rr) {
    int r = w * 4 + rr;
    int i = it * 16 + r;
    float e0 = es[(0 * 8 + b) * 1024 + i];
    float e1 = es[(1 * 8 + b) * 1024 + i];
    float e2 = es[(2 * 8 + b) * 1024 + i];
    float e3 = es[(3 * 8 + b) * 1024 + i];
    // pass 1: row max
    float mx = NINF;
    for (int k = 0; k < 16; ++k) {
      int j = k * 64 + lane;
      unsigned m = nibR[i * 1024 + j];
      float e = NINF;
      if (m) {
        int d = 31 - __clz((int)m);
        float esd = d == 0 ? e0 : d == 1 ? e1 : d == 2 ? e2 : e3;
        float z = esd + ed[(d * 8 + b) * 1024 + j];
        e = z > 0.0f ? z : 0.01f * z;
      }
      mx = fmaxf(mx, e);
    }
    for (int off = 32; off; off >>= 1) mx = fmaxf(mx, __shfl_xor(mx, off));
    // pass 2: exp + sum, store unnormalized p (bf16) to LDS
    float s = 0.f;
    for (int k = 0; k < 16; ++k) {
      int j = k * 64 + lane;
      unsigned m = nibR[i * 1024 + j];
      float e = NINF;
      if (m) {
        int d = 31 - __clz((int)m);
        float esd = d == 0 ? e0 : d == 1 ? e1 : d == 2 ? e2 : e3;
        float z = esd + ed[(d * 8 + b) * 1024 + j];
        e = z > 0.0f ? z : 0.01f * z;
      }
      float p = exp2f((e - mx) * 1.4426950408889634f);
      s += p;
      sAl[r][j] = f2bf(p);
    }
    for (int off = 32; off; off >>= 1) s += __shfl_xor(s, off);
    if (lane == 0) srs[r] = 1.0f / s;
  }
  __syncthreads();
  // frag-ordered write: alphaF[b][it][jw][lane][8]
#pragma unroll
  for (int cc = 0; cc < 8; ++cc) {
    int c = cc * 256 + t;
    int jw = c >> 6, l = c & 63;
    int i_l = l & 15;
    int j_l = jw * 32 + (l >> 4) * 8;
    uint4 v = *(const uint4*)&sAl[i_l][j_l];
    float rs = srs[i_l];
    u16 pk[8] __attribute__((aligned(16)));
    u32 wv[4] = {v.x, v.y, v.z, v.w};
#pragma unroll
    for (int k = 0; k < 4; ++k) {
      pk[k * 2] = f2bf(bf2f((u16)(wv[k] & 0xFFFFu)) * rs);
      pk[k * 2 + 1] = f2bf(bf2f((u16)(wv[k] >> 16)) * rs);
    }
    int off = (((b * 64 + it) * 32 + jw) * 64 + l) * 8;
    *(uint4*)&alphaF[off] = *(uint4*)pk;
  }
}

// ---------------------------------------------------------------------------
// K6: part[ks][b,i,o] (bf16) = sum over ks-quarter of j of
//     sum_d (alpha .* M_d) @ Whst[d,b]^T.  All operands frag-ordered ->
// every load is lane-contiguous (8 lines/instr). No LDS, no barriers.
// A+nib double-buffered per js; B 3-slot rotation, 2-step lookahead.
__global__ __launch_bounds__(256, 2) void k_agg(const u16* __restrict__ alphaF,
                                                const unsigned char* __restrict__ nibF,
                                                const u16* __restrict__ WhstF,
                                                u16* __restrict__ part) {
  int ob2 = blockIdx.x;        // 2: o-half (8 o-tiles each)
  int bz = blockIdx.y;         // 32: b*4 + ks
  int iz = blockIdx.z;         // 8: i-tile-128
  int b = bz >> 2, ks = bz & 3;
  int t = threadIdx.x, lane = t & 63, w = t >> 6;
  int wm = w >> 1, wn = w & 1;
  int r16 = lane & 15, quad = lane >> 4;
  int itb = iz * 8 + wm * 4;   // first of 4 i-tiles for this wave
  int otb = ob2 * 8 + wn * 4;  // first of 4 o-tiles
  int jw0 = ks * 8;

  int aoff[4], noff[4], bo[4];
#pragma unroll
  for (int tm = 0; tm < 4; ++tm) {
    aoff[tm] = (((b * 64 + itb + tm) * 32 + jw0) * 64 + lane) * 8;
    noff[tm] = (((itb + tm) * 32 + jw0) * 64 + lane) * 8;
  }
#pragma unroll
  for (int d = 0; d < 4; ++d)
    bo[d] = ((((d * 8 + b) * 16 + otb) * 32 + jw0) * 64 + lane) * 8;

  f4 acc[4][4];
  const f4 fz = {0.f, 0.f, 0.f, 0.f};
#pragma unroll
  for (int i = 0; i < 4; ++i)
#pragma unroll
    for (int j = 0; j < 4; ++j) acc[i][j] = fz;

  uint4 A[2][4];
  uint2 Nn[2][4];
  uint4 Bb[3][4];
  union U { uint4 u; bf8 h; };

#pragma unroll
  for (int tm = 0; tm < 4; ++tm) {
    A[0][tm] = *(const uint4*)&alphaF[aoff[tm]];
    Nn[0][tm] = *(const uint2*)&nibF[noff[tm]];
  }
#pragma unroll
  for (int tn = 0; tn < 4; ++tn) {
    Bb[0][tn] = *(const uint4*)&WhstF[bo[0] + tn * 16384];
    Bb[1][tn] = *(const uint4*)&WhstF[bo[1] + tn * 16384];
  }

#pragma unroll
  for (int js = 0; js < 8; ++js) {
    int cs = js & 1;
    if (js < 7) {
#pragma unroll
      for (int tm = 0; tm < 4; ++tm) {
        A[cs ^ 1][tm] = *(const uint4*)&alphaF[aoff[tm] + (js + 1) * 512];
        Nn[cs ^ 1][tm] = *(const uint2*)&nibF[noff[tm] + (js + 1) * 512];
      }
    }
#pragma unroll
    for (int d = 0; d < 4; ++d) {
      int s = js * 4 + d;
      if (s + 2 < 32) {
        int js2 = (s + 2) >> 2, d2 = (s + 2) & 3;
#pragma unroll
        for (int tn = 0; tn < 4; ++tn)
          Bb[(s + 2) % 3][tn] = *(const uint4*)&WhstF[bo[d2] + js2 * 512 + tn * 16384];
      }
      U af[4];
#pragma unroll
      for (int tm = 0; tm < 4; ++tm) {
        uint2 mb = Nn[cs][tm];
        u32 e0 = ((mb.x >> d) & 0x01010101u) * 0xFFu;
        u32 e1 = ((mb.y >> d) & 0x01010101u) * 0xFFu;
        af[tm].u.x = A[cs][tm].x & dup01(e0);
        af[tm].u.y = A[cs][tm].y & dup23(e0);
        af[tm].u.z = A[cs][tm].z & dup01(e1);
        af[tm].u.w = A[cs][tm].w & dup23(e1);
      }
#pragma unroll
      for (int tm = 0; tm < 4; ++tm)
#pragma unroll
        for (int tn = 0; tn < 4; ++tn) {
          U bb; bb.u = Bb[s % 3][tn];
          acc[tm][tn] = __builtin_amdgcn_mfma_f32_16x16x32_bf16(
              af[tm].h, bb.h, acc[tm][tn], 0, 0, 0);
        }
    }
  }
  // epilogue: bf16 partials [ks][b][i][o]
  u16* P = part + (size_t)ks * 2097152;
#pragma unroll
  for (int tm = 0; tm < 4; ++tm) {
#pragma unroll
    for (int tn = 0; tn < 4; ++tn) {
      int irow = (itb + tm) * 16 + quad * 4;
      int go = (otb + tn) * 16 + r16;
#pragma unroll
      for (int r = 0; r < 4; ++r)
        P[((size_t)b * 1024 + irow + r) * 256 + go] = f2bf(acc[tm][tn][r]);
    }
  }
}

// ---------------------------------------------------------------------------
// K7: out = 0.5 * sum_ks part[ks]  (bf16 -> fp32)
__global__ void k_reduce(const u16* __restrict__ part, float* __restrict__ out) {
  int idx = (blockIdx.x * 256 + threadIdx.x) * 8;
  float s[8];
#pragma unroll
  for (int k = 0; k < 8; ++k) s[k] = 0.f;
#pragma unroll
  for (int ks = 0; ks < 4; ++ks) {
    uint4 v = *(const uint4*)&part[(size_t)ks * 2097152 + idx];
    u32 ww[4] = {v.x, v.y, v.z, v.w};
#pragma unroll
    for (int k = 0; k < 4; ++k) {
      union { u32 i; float f; } lo, hi;
      lo.i = (ww[k] & 0xFFFFu) << 16;
      hi.i = ww[k] & 0xFFFF0000u;
      s[k * 2] += lo.f;
      s[k * 2 + 1] += hi.f;
    }
  }
  float4 o0 = {0.5f * s[0], 0.5f * s[1], 0.5f * s[2], 0.5f * s[3]};
  float4 o1 = {0.5f * s[4], 0.5f * s[5], 0.5f * s[6], 0.5f * s[7]};
  *(float4*)&out[idx] = o0;
  *(float4*)&out[idx + 4] = o1;
}

// ---------------------------------------------------------------------------
extern "C" void kernel_launch(void* const* d_in, const int* in_sizes, int n_in,
                              void* d_out, int out_size, void* d_ws, size_t ws_size,
                              hipStream_t stream) {
  const float* x = (const float*)d_in[0];
  const int* AU = (const int*)d_in[1];
  const int* AD = (const int*)d_in[2];
  const int* AR = (const int*)d_in[3];
  const int* AL = (const int*)d_in[4];
  const float* W = (const float*)d_in[5];
  const float* a = (const float*)d_in[6];
  float* out = (float*)d_out;

  char* ws = (char*)d_ws;
  // workspace layout (bytes) — total ~57.4 MB (<= 64.76 MB proven)
  u16* Wt = (u16*)(ws + 0);                      // 512 KB
  float* vsrc = (float*)(ws + 524288);           //   4 KB
  float* vdst = (float*)(ws + 528384);           //   4 KB
  float* es = (float*)(ws + 532480);             // 128 KB
  float* ed = (float*)(ws + 663552);             // 128 KB
  unsigned char* nibR = (unsigned char*)(ws + 794624);   // 1 MB row-major nibbles
  unsigned char* nibF = (unsigned char*)(ws + 1843200);  // 1 MB frag-order nibbles
  u16* xb = (u16*)(ws + 2891776);                //   4 MB bf16 x
  u16* WhstF = (u16*)(ws + 7086080);             //  16 MB frag-order Whst
  u16* alphaF = (u16*)(ws + 23863296);           //  16 MB frag-order alpha
  u16* part = (u16*)(ws + 40640512);             //  16 MB bf16 split-K partials
  if (ws_size < 57417728) return;

  hipLaunchKernelGGL(k_transpose, dim3(16, 4), dim3(256), 0, stream, W, Wt);
  hipLaunchKernelGGL(k_vsd, dim3(1024), dim3(256), 0, stream, W, a, vsrc, vdst);
  hipLaunchKernelGGL(k_edots, dim3(8192), dim3(256), 0, stream, x, vsrc, vdst, es, ed, xb);
  hipLaunchKernelGGL(k_mask, dim3(512), dim3(256), 0, stream, AU, AD, AR, AL, nibR, nibF);
  hipLaunchKernelGGL(k_whsum, dim3(2, 64, 4), dim3(256), 0, stream, xb, Wt, WhstF);
  hipLaunchKernelGGL(k_softmax, dim3(64, 8), dim3(256), 0, stream, es, ed, nibR, alphaF);
  hipLaunchKernelGGL(k_agg, dim3(2, 32, 8), dim3(256), 0, stream, alphaF, nibF, WhstF, part);
  hipLaunchKernelGGL(k_reduce, dim3(1024), dim3(256), 0, stream, part, out);
}

// Round 7
// 174.538 us; speedup vs baseline: 3.0686x; 1.1848x over previous
//
#include <hip/hip_runtime.h>

// Problem constants
#define B_ 8
#define N_ 1024
#define F_ 256
#define O_ 256

typedef unsigned short u16;
typedef unsigned int u32;
typedef __attribute__((ext_vector_type(8))) short bf8;   // 8 bf16 (4 VGPRs) MFMA frag
typedef __attribute__((ext_vector_type(4))) float f4;    // 4 fp32 MFMA acc

__device__ __forceinline__ u16 f2bf(float f) {
  union { float f; u32 u; } c; c.f = f;
  u32 u = c.u;
  u32 r = u + 0x7FFFu + ((u >> 16) & 1u);  // RNE
  return (u16)(r >> 16);
}
__device__ __forceinline__ float bf2f(u16 u) {
  union { u32 i; float f; } c; c.i = ((u32)u) << 16; return c.f;
}

// byte-dup halfword-mask expansion: e bytes are 0x00/0xFF per j; W = halfword
// masks for j-pairs. v_perm if available, arithmetic fallback otherwise.
#if defined(__has_builtin)
#if __has_builtin(__builtin_amdgcn_perm)
#define HAVE_PERM 1
#endif
#endif
__device__ __forceinline__ u32 dup01(u32 e) {  // bytes (b0,b0,b1,b1)
#ifdef HAVE_PERM
  return __builtin_amdgcn_perm(e, e, 0x01010000u);
#else
  return (e & 0xFFu) * 0x0101u + (e & 0xFF00u) * 0x010100u;
#endif
}
__device__ __forceinline__ u32 dup23(u32 e) {  // bytes (b2,b2,b3,b3)
#ifdef HAVE_PERM
  return __builtin_amdgcn_perm(e, e, 0x03030202u);
#else
  return ((e >> 16) & 0xFFu) * 0x0101u + ((e >> 16) & 0xFF00u) * 0x010100u;
#endif
}

// ---------------------------------------------------------------------------
// K1a: Wt[d][o][f] (bf16) = transpose of (W[d,0]+W[d,1]) — head-sum folded in.
__global__ void k_transpose(const float* __restrict__ W, u16* __restrict__ Wt) {
  __shared__ u16 t[64][72];
  int d = blockIdx.y;
  int tile = blockIdx.x;
  int f0 = (tile >> 2) * 64, o0 = (tile & 3) * 64;
  const float* src0 = W + (d * 2 + 0) * 65536;
  const float* src1 = W + (d * 2 + 1) * 65536;
  u16* dst = Wt + d * 65536;
  int tdx = threadIdx.x;
  for (int i = 0; i < 2; ++i) {
    int c = i * 256 + tdx;
    int row = c >> 3, cc = (c & 7) * 8;
    int base = (f0 + row) * 256 + o0 + cc;
    float4 a0 = *(const float4*)&src0[base];
    float4 a1 = *(const float4*)&src0[base + 4];
    float4 b0 = *(const float4*)&src1[base];
    float4 b1 = *(const float4*)&src1[base + 4];
    u16 tmp[8] __attribute__((aligned(16)));
    tmp[0] = f2bf(a0.x + b0.x); tmp[1] = f2bf(a0.y + b0.y);
    tmp[2] = f2bf(a0.z + b0.z); tmp[3] = f2bf(a0.w + b0.w);
    tmp[4] = f2bf(a1.x + b1.x); tmp[5] = f2bf(a1.y + b1.y);
    tmp[6] = f2bf(a1.z + b1.z); tmp[7] = f2bf(a1.w + b1.w);
    *(uint4*)&t[row][cc] = *(uint4*)tmp;
  }
  __syncthreads();
  for (int i = 0; i < 2; ++i) {
    int c = i * 256 + tdx;
    int orow = c >> 3, fc = (c & 7) * 8;
    u16 v[8] __attribute__((aligned(16)));
#pragma unroll
    for (int k = 0; k < 8; ++k) v[k] = t[fc + k][orow];
    *(uint4*)&dst[(o0 + orow) * 256 + f0 + fc] = *(uint4*)v;
  }
}

// ---------------------------------------------------------------------------
// K1b: vsrc[d][f] = sum_o W[d,1,f,o]*a[d,1,o] ; vdst with a[d,1,256+o].
__global__ void k_vsd(const float* __restrict__ W, const float* __restrict__ a,
                      float* __restrict__ vsrc, float* __restrict__ vdst) {
  int blk = blockIdx.x;
  int d = blk >> 8, f = blk & 255;
  int o = threadIdx.x;
  int dh = d * 2 + 1;
  float w = W[(dh * 256 + f) * 256 + o];
  float as = a[dh * 512 + o];
  float ad = a[dh * 512 + 256 + o];
  float ps = w * as, pd = w * ad;
  __shared__ float red[2][4];
  for (int off = 32; off; off >>= 1) {
    ps += __shfl_down(ps, off);
    pd += __shfl_down(pd, off);
  }
  int lane = o & 63, w4 = o >> 6;
  if (lane == 0) { red[0][w4] = ps; red[1][w4] = pd; }
  __syncthreads();
  if (o == 0) vsrc[d * 256 + f] = red[0][0] + red[0][1] + red[0][2] + red[0][3];
  if (o == 1) vdst[d * 256 + f] = red[1][0] + red[1][1] + red[1][2] + red[1][3];
}

// ---------------------------------------------------------------------------
// K2: e_src/e_dst dots + xb = bf16(x). One block per (b,n).
__global__ void k_edots(const float* __restrict__ x, const float* __restrict__ vsrc,
                        const float* __restrict__ vdst, float* __restrict__ es,
                        float* __restrict__ ed, u16* __restrict__ xb) {
  int row = blockIdx.x;
  int f = threadIdx.x;
  float xv = x[(size_t)row * 256 + f];
  xb[(size_t)row * 256 + f] = f2bf(xv);
  float p[8];
#pragma unroll
  for (int d = 0; d < 4; ++d) {
    p[d] = xv * vsrc[d * 256 + f];
    p[4 + d] = xv * vdst[d * 256 + f];
  }
#pragma unroll
  for (int v = 0; v < 8; ++v)
    for (int off = 32; off; off >>= 1) p[v] += __shfl_down(p[v], off);
  __shared__ float red[8][4];
  int lane = f & 63, w4 = f >> 6;
  if (lane == 0) {
    for (int v = 0; v < 8; ++v) red[v][w4] = p[v];
  }
  __syncthreads();
  if (f < 8) {
    float s = red[f][0] + red[f][1] + red[f][2] + red[f][3];
    int d = f & 3;
    int b = row >> 10, n = row & 1023;
    float* dstp = (f < 4) ? es : ed;
    dstp[(d * 8 + b) * 1024 + n] = s;
  }
}

// ---------------------------------------------------------------------------
// K4: nibble masks (4 bits per (i,j), one byte each) in row-major (nibR, for
// softmax) and frag order (nibF, for k_agg).
__global__ void k_mask(const int* __restrict__ AU, const int* __restrict__ AD,
                       const int* __restrict__ AR, const int* __restrict__ AL,
                       unsigned char* __restrict__ nibR, unsigned char* __restrict__ nibF) {
  int idx = blockIdx.x * 256 + threadIdx.x;  // 131072: i*128 + j/8
  int i = idx >> 7;
  int jb = (idx & 127) * 8;
  int base = i * 1024 + jb;
  int4 au0 = *(const int4*)&AU[base], au1 = *(const int4*)&AU[base + 4];
  int4 ad0 = *(const int4*)&AD[base], ad1 = *(const int4*)&AD[base + 4];
  int4 ar0 = *(const int4*)&AR[base], ar1 = *(const int4*)&AR[base + 4];
  int4 al0 = *(const int4*)&AL[base], al1 = *(const int4*)&AL[base + 4];
  int u[8] = {au0.x, au0.y, au0.z, au0.w, au1.x, au1.y, au1.z, au1.w};
  int dn[8] = {ad0.x, ad0.y, ad0.z, ad0.w, ad1.x, ad1.y, ad1.z, ad1.w};
  int rr[8] = {ar0.x, ar0.y, ar0.z, ar0.w, ar1.x, ar1.y, ar1.z, ar1.w};
  int ll[8] = {al0.x, al0.y, al0.z, al0.w, al1.x, al1.y, al1.z, al1.w};
  unsigned char m[8] __attribute__((aligned(8)));
#pragma unroll
  for (int k = 0; k < 8; ++k)
    m[k] = (unsigned char)((u[k] ? 1u : 0u) | (dn[k] ? 2u : 0u) | (rr[k] ? 4u : 0u) | (ll[k] ? 8u : 0u));
  *(uint2*)&nibR[base] = *(uint2*)m;
  int it = i >> 4, jw = jb >> 5;
  int lane = ((jb >> 3) & 3) * 16 + (i & 15);
  *(uint2*)&nibF[((it * 32 + jw) * 64 + lane) * 8] = *(uint2*)m;
}

// ---------------------------------------------------------------------------
// K3: WhstF = frag-ordered bf16 of (Xb @ Wtsum[d])^T.
// WhstF[d][b][ot16][jw32][lane64][8j]: frag loads in k_agg are lane-contiguous.
__global__ __launch_bounds__(256, 2) void k_whsum(const u16* __restrict__ X,
                                                  const u16* __restrict__ Wt,
                                                  u16* __restrict__ WhstF) {
  __shared__ u16 lA[128 * 32];
  __shared__ u16 lB[128 * 32];
  __shared__ u16 sC[128 * 136];
  int d = blockIdx.z;
  int m0 = blockIdx.y * 128;
  int o0 = blockIdx.x * 128;
  int t = threadIdx.x;
  int lane = t & 63, w = t >> 6;
  int wm = w >> 1, wn = w & 1;
  int r16 = lane & 15, quad = lane >> 4, q8 = quad * 8;
  f4 acc[4][4];
  const f4 fz = {0.f, 0.f, 0.f, 0.f};
#pragma unroll
  for (int i = 0; i < 4; ++i)
#pragma unroll
    for (int j = 0; j < 4; ++j) acc[i][j] = fz;

  const u16* Bp = Wt + d * 65536;
  for (int k0 = 0; k0 < 256; k0 += 32) {
    uint4 va[2], vb[2];
#pragma unroll
    for (int i = 0; i < 2; ++i) {
      int c = i * 256 + t;
      int row = c >> 2, ko = (c & 3) * 8;
      va[i] = *(const uint4*)&X[(size_t)(m0 + row) * 256 + k0 + ko];
      vb[i] = *(const uint4*)&Bp[(o0 + row) * 256 + k0 + ko];
    }
    __syncthreads();
#pragma unroll
    for (int i = 0; i < 2; ++i) {
      int c = i * 256 + t;
      *(uint4*)&lA[c * 8] = va[i];
      *(uint4*)&lB[c * 8] = vb[i];
    }
    __syncthreads();
    bf8 af[4], bfr[4];
#pragma unroll
    for (int tm = 0; tm < 4; ++tm)
      af[tm] = *(const bf8*)&lA[(wm * 64 + tm * 16 + r16) * 32 + q8];
#pragma unroll
    for (int tn = 0; tn < 4; ++tn)
      bfr[tn] = *(const bf8*)&lB[(wn * 64 + tn * 16 + r16) * 32 + q8];
#pragma unroll
    for (int tm = 0; tm < 4; ++tm)
#pragma unroll
      for (int tn = 0; tn < 4; ++tn)
        acc[tm][tn] = __builtin_amdgcn_mfma_f32_16x16x32_bf16(
            af[tm], bfr[tn], acc[tm][tn], 0, 0, 0);
  }
  // stage C tile [o][n] in LDS
#pragma unroll
  for (int tm = 0; tm < 4; ++tm) {
#pragma unroll
    for (int tn = 0; tn < 4; ++tn) {
      int o = wn * 64 + tn * 16 + r16;
      int n = wm * 64 + tm * 16 + quad * 4;
      u16 p[4] __attribute__((aligned(8)));
#pragma unroll
      for (int r = 0; r < 4; ++r) p[r] = f2bf(acc[tm][tn][r]);
      *(uint2*)&sC[o * 136 + n] = *(uint2*)p;
    }
  }
  __syncthreads();
  int b = m0 >> 10;
  int nlo = m0 & 1023;
  int dbbase = d * 8 + b;
  int otg0 = o0 >> 4, jwg0 = nlo >> 5;
#pragma unroll
  for (int cc = 0; cc < 8; ++cc) {
    int c = cc * 256 + t;
    int p = c >> 6, l = c & 63;
    int ot_l = p >> 2, jw_l = p & 3;
    int o_l = ot_l * 16 + (l & 15);
    int j_l = jw_l * 32 + (l >> 4) * 8;
    uint4 v = *(const uint4*)&sC[o_l * 136 + j_l];
    int off = (((dbbase * 16 + otg0 + ot_l) * 32 + jwg0 + jw_l) * 64 + l) * 8;
    *(uint4*)&WhstF[off] = v;
  }
}

// ---------------------------------------------------------------------------
// K5 (R7 rewrite): softmax -> alphaF (frag-ordered bf16).
// Latency fixes vs R6: ed cached in LDS (the data-dependent gather becomes a
// conflict-free ds_read), nib row loaded once into registers, single fused
// pass with e[16] held in VGPRs.
__global__ __launch_bounds__(256) void k_softmax(const float* __restrict__ es,
                                                 const float* __restrict__ ed,
                                                 const unsigned char* __restrict__ nibR,
                                                 u16* __restrict__ alphaF) {
  __shared__ float sEd[4 * 1024];  // 16 KB: ed[d][j] for this b
  __shared__ u16 sAl[16][1032];    // 33 KB: unnormalized p, padded stride
  __shared__ float srs[16];
  int it = blockIdx.x, b = blockIdx.y;
  int t = threadIdx.x, lane = t & 63, w = t >> 6;
  const float NINF = -__builtin_inff();
  // stage ed (coalesced float4)
#pragma unroll
  for (int c = 0; c < 4; ++c) {
    int q = c * 256 + t;              // 1024 float4 chunks
    int d = q >> 8, jc = (q & 255) * 4;
    *(float4*)&sEd[d * 1024 + jc] = *(const float4*)&ed[(size_t)(d * 8 + b) * 1024 + jc];
  }
  __syncthreads();
  for (int rr = 0; rr < 4; ++rr) {
    int r = w * 4 + rr;
    int i = it * 16 + r;
    float e0 = es[(0 * 8 + b) * 1024 + i];
    float e1 = es[(1 * 8 + b) * 1024 + i];
    float e2 = es[(2 * 8 + b) * 1024 + i];
    float e3 = es[(3 * 8 + b) * 1024 + i];
    // batch the 16 nib loads (independent, coalesced 64B each)
    unsigned mbv[16];
#pragma unroll
    for (int k = 0; k < 16; ++k) mbv[k] = nibR[i * 1024 + k * 64 + lane];
    // single pass: e[k] in registers
    float e[16];
    float mx = NINF;
#pragma unroll
    for (int k = 0; k < 16; ++k) {
      unsigned m = mbv[k];
      int d = m ? (31 - __clz((int)m)) : 0;
      float esd = d == 0 ? e0 : d == 1 ? e1 : d == 2 ? e2 : e3;
      float z = esd + sEd[d * 1024 + k * 64 + lane];
      float lz = z > 0.0f ? z : 0.01f * z;
      e[k] = m ? lz : NINF;
      mx = fmaxf(mx, e[k]);
    }
    for (int off = 32; off; off >>= 1) mx = fmaxf(mx, __shfl_xor(mx, off));
    float s = 0.f;
#pragma unroll
    for (int k = 0; k < 16; ++k) {
      float p = exp2f((e[k] - mx) * 1.4426950408889634f);  // exp(-inf)=0 masked
      s += p;
      sAl[r][k * 64 + lane] = f2bf(p);
    }
    for (int off = 32; off; off >>= 1) s += __shfl_xor(s, off);
    if (lane == 0) srs[r] = 1.0f / s;
  }
  __syncthreads();
  // frag-ordered write: alphaF[b][it][jw][lane][8]
#pragma unroll
  for (int cc = 0; cc < 8; ++cc) {
    int c = cc * 256 + t;
    int jw = c >> 6, l = c & 63;
    int i_l = l & 15;
    int j_l = jw * 32 + (l >> 4) * 8;
    uint4 v = *(const uint4*)&sAl[i_l][j_l];
    float rs = srs[i_l];
    u16 pk[8] __attribute__((aligned(16)));
    u32 wv[4] = {v.x, v.y, v.z, v.w};
#pragma unroll
    for (int k = 0; k < 4; ++k) {
      pk[k * 2] = f2bf(bf2f((u16)(wv[k] & 0xFFFFu)) * rs);
      pk[k * 2 + 1] = f2bf(bf2f((u16)(wv[k] >> 16)) * rs);
    }
    int off = (((b * 64 + it) * 32 + jw) * 64 + l) * 8;
    *(uint4*)&alphaF[off] = *(uint4*)pk;
  }
}

// ---------------------------------------------------------------------------
// K6: part[ks][b,i,o] (bf16) = sum over ks-quarter of j of
//     sum_d (alpha .* M_d) @ Whst[d,b]^T.  All operands frag-ordered ->
// every load is lane-contiguous (8 lines/instr). No LDS, no barriers.
// A+nib double-buffered per js; B 3-slot rotation, 2-step lookahead.
__global__ __launch_bounds__(256, 2) void k_agg(const u16* __restrict__ alphaF,
                                                const unsigned char* __restrict__ nibF,
                                                const u16* __restrict__ WhstF,
                                                u16* __restrict__ part) {
  int ob2 = blockIdx.x;        // 2: o-half (8 o-tiles each)
  int bz = blockIdx.y;         // 32: b*4 + ks
  int iz = blockIdx.z;         // 8: i-tile-128
  int b = bz >> 2, ks = bz & 3;
  int t = threadIdx.x, lane = t & 63, w = t >> 6;
  int wm = w >> 1, wn = w & 1;
  int r16 = lane & 15, quad = lane >> 4;
  int itb = iz * 8 + wm * 4;   // first of 4 i-tiles for this wave
  int otb = ob2 * 8 + wn * 4;  // first of 4 o-tiles
  int jw0 = ks * 8;

  int aoff[4], noff[4], bo[4];
#pragma unroll
  for (int tm = 0; tm < 4; ++tm) {
    aoff[tm] = (((b * 64 + itb + tm) * 32 + jw0) * 64 + lane) * 8;
    noff[tm] = (((itb + tm) * 32 + jw0) * 64 + lane) * 8;
  }
#pragma unroll
  for (int d = 0; d < 4; ++d)
    bo[d] = ((((d * 8 + b) * 16 + otb) * 32 + jw0) * 64 + lane) * 8;

  f4 acc[4][4];
  const f4 fz = {0.f, 0.f, 0.f, 0.f};
#pragma unroll
  for (int i = 0; i < 4; ++i)
#pragma unroll
    for (int j = 0; j < 4; ++j) acc[i][j] = fz;

  uint4 A[2][4];
  uint2 Nn[2][4];
  uint4 Bb[3][4];
  union U { uint4 u; bf8 h; };

#pragma unroll
  for (int tm = 0; tm < 4; ++tm) {
    A[0][tm] = *(const uint4*)&alphaF[aoff[tm]];
    Nn[0][tm] = *(const uint2*)&nibF[noff[tm]];
  }
#pragma unroll
  for (int tn = 0; tn < 4; ++tn) {
    Bb[0][tn] = *(const uint4*)&WhstF[bo[0] + tn * 16384];
    Bb[1][tn] = *(const uint4*)&WhstF[bo[1] + tn * 16384];
  }

#pragma unroll
  for (int js = 0; js < 8; ++js) {
    int cs = js & 1;
    if (js < 7) {
#pragma unroll
      for (int tm = 0; tm < 4; ++tm) {
        A[cs ^ 1][tm] = *(const uint4*)&alphaF[aoff[tm] + (js + 1) * 512];
        Nn[cs ^ 1][tm] = *(const uint2*)&nibF[noff[tm] + (js + 1) * 512];
      }
    }
#pragma unroll
    for (int d = 0; d < 4; ++d) {
      int s = js * 4 + d;
      if (s + 2 < 32) {
        int js2 = (s + 2) >> 2, d2 = (s + 2) & 3;
#pragma unroll
        for (int tn = 0; tn < 4; ++tn)
          Bb[(s + 2) % 3][tn] = *(const uint4*)&WhstF[bo[d2] + js2 * 512 + tn * 16384];
      }
      U af[4];
#pragma unroll
      for (int tm = 0; tm < 4; ++tm) {
        uint2 mb = Nn[cs][tm];
        u32 e0 = ((mb.x >> d) & 0x01010101u) * 0xFFu;
        u32 e1 = ((mb.y >> d) & 0x01010101u) * 0xFFu;
        af[tm].u.x = A[cs][tm].x & dup01(e0);
        af[tm].u.y = A[cs][tm].y & dup23(e0);
        af[tm].u.z = A[cs][tm].z & dup01(e1);
        af[tm].u.w = A[cs][tm].w & dup23(e1);
      }
#pragma unroll
      for (int tm = 0; tm < 4; ++tm)
#pragma unroll
        for (int tn = 0; tn < 4; ++tn) {
          U bb; bb.u = Bb[s % 3][tn];
          acc[tm][tn] = __builtin_amdgcn_mfma_f32_16x16x32_bf16(
              af[tm].h, bb.h, acc[tm][tn], 0, 0, 0);
        }
    }
  }
  // epilogue: bf16 partials [ks][b][i][o]
  u16* P = part + (size_t)ks * 2097152;
#pragma unroll
  for (int tm = 0; tm < 4; ++tm) {
#pragma unroll
    for (int tn = 0; tn < 4; ++tn) {
      int irow = (itb + tm) * 16 + quad * 4;
      int go = (otb + tn) * 16 + r16;
#pragma unroll
      for (int r = 0; r < 4; ++r)
        P[((size_t)b * 1024 + irow + r) * 256 + go] = f2bf(acc[tm][tn][r]);
    }
  }
}

// ---------------------------------------------------------------------------
// K7: out = 0.5 * sum_ks part[ks]  (bf16 -> fp32)
__global__ void k_reduce(const u16* __restrict__ part, float* __restrict__ out) {
  int idx = (blockIdx.x * 256 + threadIdx.x) * 8;
  float s[8];
#pragma unroll
  for (int k = 0; k < 8; ++k) s[k] = 0.f;
#pragma unroll
  for (int ks = 0; ks < 4; ++ks) {
    uint4 v = *(const uint4*)&part[(size_t)ks * 2097152 + idx];
    u32 ww[4] = {v.x, v.y, v.z, v.w};
#pragma unroll
    for (int k = 0; k < 4; ++k) {
      union { u32 i; float f; } lo, hi;
      lo.i = (ww[k] & 0xFFFFu) << 16;
      hi.i = ww[k] & 0xFFFF0000u;
      s[k * 2] += lo.f;
      s[k * 2 + 1] += hi.f;
    }
  }
  float4 o0 = {0.5f * s[0], 0.5f * s[1], 0.5f * s[2], 0.5f * s[3]};
  float4 o1 = {0.5f * s[4], 0.5f * s[5], 0.5f * s[6], 0.5f * s[7]};
  *(float4*)&out[idx] = o0;
  *(float4*)&out[idx + 4] = o1;
}

// ---------------------------------------------------------------------------
extern "C" void kernel_launch(void* const* d_in, const int* in_sizes, int n_in,
                              void* d_out, int out_size, void* d_ws, size_t ws_size,
                              hipStream_t stream) {
  const float* x = (const float*)d_in[0];
  const int* AU = (const int*)d_in[1];
  const int* AD = (const int*)d_in[2];
  const int* AR = (const int*)d_in[3];
  const int* AL = (const int*)d_in[4];
  const float* W = (const float*)d_in[5];
  const float* a = (const float*)d_in[6];
  float* out = (float*)d_out;

  char* ws = (char*)d_ws;
  // workspace layout (bytes) — total ~57.4 MB (<= 64.76 MB proven)
  u16* Wt = (u16*)(ws + 0);                      // 512 KB
  float* vsrc = (float*)(ws + 524288);           //   4 KB
  float* vdst = (float*)(ws + 528384);           //   4 KB
  float* es = (float*)(ws + 532480);             // 128 KB
  float* ed = (float*)(ws + 663552);             // 128 KB
  unsigned char* nibR = (unsigned char*)(ws + 794624);   // 1 MB row-major nibbles
  unsigned char* nibF = (unsigned char*)(ws + 1843200);  // 1 MB frag-order nibbles
  u16* xb = (u16*)(ws + 2891776);                //   4 MB bf16 x
  u16* WhstF = (u16*)(ws + 7086080);             //  16 MB frag-order Whst
  u16* alphaF = (u16*)(ws + 23863296);           //  16 MB frag-order alpha
  u16* part = (u16*)(ws + 40640512);             //  16 MB bf16 split-K partials
  if (ws_size < 57417728) return;

  hipLaunchKernelGGL(k_transpose, dim3(16, 4), dim3(256), 0, stream, W, Wt);
  hipLaunchKernelGGL(k_vsd, dim3(1024), dim3(256), 0, stream, W, a, vsrc, vdst);
  hipLaunchKernelGGL(k_edots, dim3(8192), dim3(256), 0, stream, x, vsrc, vdst, es, ed, xb);
  hipLaunchKernelGGL(k_mask, dim3(512), dim3(256), 0, stream, AU, AD, AR, AL, nibR, nibF);
  hipLaunchKernelGGL(k_whsum, dim3(2, 64, 4), dim3(256), 0, stream, xb, Wt, WhstF);
  hipLaunchKernelGGL(k_softmax, dim3(64, 8), dim3(256), 0, stream, es, ed, nibR, alphaF);
  hipLaunchKernelGGL(k_agg, dim3(2, 32, 8), dim3(256), 0, stream, alphaF, nibF, WhstF, part);
  hipLaunchKernelGGL(k_reduce, dim3(1024), dim3(256), 0, stream, part, out);
}

// Round 8
// 161.209 us; speedup vs baseline: 3.3223x; 1.0827x over previous
//
#include <hip/hip_runtime.h>

// Problem constants
#define B_ 8
#define N_ 1024
#define F_ 256
#define O_ 256

typedef unsigned short u16;
typedef unsigned int u32;
typedef __attribute__((ext_vector_type(8))) short bf8;   // 8 bf16 (4 VGPRs) MFMA frag
typedef __attribute__((ext_vector_type(4))) float f4;    // 4 fp32 MFMA acc

__device__ __forceinline__ u16 f2bf(float f) {
  union { float f; u32 u; } c; c.f = f;
  u32 u = c.u;
  u32 r = u + 0x7FFFu + ((u >> 16) & 1u);  // RNE
  return (u16)(r >> 16);
}
__device__ __forceinline__ float bf2f(u16 u) {
  union { u32 i; float f; } c; c.i = ((u32)u) << 16; return c.f;
}

#if defined(__has_builtin)
#if __has_builtin(__builtin_amdgcn_perm)
#define HAVE_PERM 1
#endif
#endif
__device__ __forceinline__ u32 dup01(u32 e) {  // bytes (b0,b0,b1,b1)
#ifdef HAVE_PERM
  return __builtin_amdgcn_perm(e, e, 0x01010000u);
#else
  return (e & 0xFFu) * 0x0101u + (e & 0xFF00u) * 0x010100u;
#endif
}
__device__ __forceinline__ u32 dup23(u32 e) {  // bytes (b2,b2,b3,b3)
#ifdef HAVE_PERM
  return __builtin_amdgcn_perm(e, e, 0x03030202u);
#else
  return ((e >> 16) & 0xFFu) * 0x0101u + ((e >> 16) & 0xFF00u) * 0x010100u;
#endif
}

// ---------------------------------------------------------------------------
// K1a: Wt[d][o][f] (bf16) = transpose of (W[d,0]+W[d,1]) — head-sum folded in.
__global__ void k_transpose(const float* __restrict__ W, u16* __restrict__ Wt) {
  __shared__ u16 t[64][72];
  int d = blockIdx.y;
  int tile = blockIdx.x;
  int f0 = (tile >> 2) * 64, o0 = (tile & 3) * 64;
  const float* src0 = W + (d * 2 + 0) * 65536;
  const float* src1 = W + (d * 2 + 1) * 65536;
  u16* dst = Wt + d * 65536;
  int tdx = threadIdx.x;
  for (int i = 0; i < 2; ++i) {
    int c = i * 256 + tdx;
    int row = c >> 3, cc = (c & 7) * 8;
    int base = (f0 + row) * 256 + o0 + cc;
    float4 a0 = *(const float4*)&src0[base];
    float4 a1 = *(const float4*)&src0[base + 4];
    float4 b0 = *(const float4*)&src1[base];
    float4 b1 = *(const float4*)&src1[base + 4];
    u16 tmp[8] __attribute__((aligned(16)));
    tmp[0] = f2bf(a0.x + b0.x); tmp[1] = f2bf(a0.y + b0.y);
    tmp[2] = f2bf(a0.z + b0.z); tmp[3] = f2bf(a0.w + b0.w);
    tmp[4] = f2bf(a1.x + b1.x); tmp[5] = f2bf(a1.y + b1.y);
    tmp[6] = f2bf(a1.z + b1.z); tmp[7] = f2bf(a1.w + b1.w);
    *(uint4*)&t[row][cc] = *(uint4*)tmp;
  }
  __syncthreads();
  for (int i = 0; i < 2; ++i) {
    int c = i * 256 + tdx;
    int orow = c >> 3, fc = (c & 7) * 8;
    u16 v[8] __attribute__((aligned(16)));
#pragma unroll
    for (int k = 0; k < 8; ++k) v[k] = t[fc + k][orow];
    *(uint4*)&dst[(o0 + orow) * 256 + f0 + fc] = *(uint4*)v;
  }
}

// ---------------------------------------------------------------------------
// K1b: vsrc[d][f] = sum_o W[d,1,f,o]*a[d,1,o] ; vdst with a[d,1,256+o].
__global__ void k_vsd(const float* __restrict__ W, const float* __restrict__ a,
                      float* __restrict__ vsrc, float* __restrict__ vdst) {
  int blk = blockIdx.x;
  int d = blk >> 8, f = blk & 255;
  int o = threadIdx.x;
  int dh = d * 2 + 1;
  float w = W[(dh * 256 + f) * 256 + o];
  float as = a[dh * 512 + o];
  float ad = a[dh * 512 + 256 + o];
  float ps = w * as, pd = w * ad;
  __shared__ float red[2][4];
  for (int off = 32; off; off >>= 1) {
    ps += __shfl_down(ps, off);
    pd += __shfl_down(pd, off);
  }
  int lane = o & 63, w4 = o >> 6;
  if (lane == 0) { red[0][w4] = ps; red[1][w4] = pd; }
  __syncthreads();
  if (o == 0) vsrc[d * 256 + f] = red[0][0] + red[0][1] + red[0][2] + red[0][3];
  if (o == 1) vdst[d * 256 + f] = red[1][0] + red[1][1] + red[1][2] + red[1][3];
}

// ---------------------------------------------------------------------------
// K2 (R8 rewrite): wave-per-4-rows. float4 loads, v-vectors staged in regs,
// butterfly shfl reductions only (no LDS, no cross-wave traffic).
__global__ __launch_bounds__(256) void k_edots(const float* __restrict__ x,
                                               const float* __restrict__ vsrc,
                                               const float* __restrict__ vdst,
                                               float* __restrict__ es,
                                               float* __restrict__ ed,
                                               u16* __restrict__ xb) {
  int t = threadIdx.x, lane = t & 63, w = t >> 6;
  int f4i = lane * 4;
  float4 vs[4], vd[4];
#pragma unroll
  for (int d = 0; d < 4; ++d) {
    vs[d] = *(const float4*)&vsrc[d * 256 + f4i];
    vd[d] = *(const float4*)&vdst[d * 256 + f4i];
  }
  int row0 = blockIdx.x * 16 + w * 4;  // 512 blocks x 16 rows
  for (int rr = 0; rr < 4; ++rr) {
    int row = row0 + rr;
    float4 xv = *(const float4*)&x[(size_t)row * 256 + f4i];
    u16 pk[4] __attribute__((aligned(8)));
    pk[0] = f2bf(xv.x); pk[1] = f2bf(xv.y); pk[2] = f2bf(xv.z); pk[3] = f2bf(xv.w);
    *(uint2*)&xb[(size_t)row * 256 + f4i] = *(uint2*)pk;
    float p[8];
#pragma unroll
    for (int d = 0; d < 4; ++d) {
      p[d] = xv.x * vs[d].x + xv.y * vs[d].y + xv.z * vs[d].z + xv.w * vs[d].w;
      p[4 + d] = xv.x * vd[d].x + xv.y * vd[d].y + xv.z * vd[d].z + xv.w * vd[d].w;
    }
#pragma unroll
    for (int v = 0; v < 8; ++v)
      for (int off = 32; off; off >>= 1) p[v] += __shfl_xor(p[v], off);
    if (lane == 0) {
      int b = row >> 10, n = row & 1023;
#pragma unroll
      for (int d = 0; d < 4; ++d) {
        es[(d * 8 + b) * 1024 + n] = p[d];
        ed[(d * 8 + b) * 1024 + n] = p[4 + d];
      }
    }
  }
}

// ---------------------------------------------------------------------------
// K4: nibble masks in row-major (nibR) and frag order (nibF).
__global__ void k_mask(const int* __restrict__ AU, const int* __restrict__ AD,
                       const int* __restrict__ AR, const int* __restrict__ AL,
                       unsigned char* __restrict__ nibR, unsigned char* __restrict__ nibF) {
  int idx = blockIdx.x * 256 + threadIdx.x;  // 131072: i*128 + j/8
  int i = idx >> 7;
  int jb = (idx & 127) * 8;
  int base = i * 1024 + jb;
  int4 au0 = *(const int4*)&AU[base], au1 = *(const int4*)&AU[base + 4];
  int4 ad0 = *(const int4*)&AD[base], ad1 = *(const int4*)&AD[base + 4];
  int4 ar0 = *(const int4*)&AR[base], ar1 = *(const int4*)&AR[base + 4];
  int4 al0 = *(const int4*)&AL[base], al1 = *(const int4*)&AL[base + 4];
  int u[8] = {au0.x, au0.y, au0.z, au0.w, au1.x, au1.y, au1.z, au1.w};
  int dn[8] = {ad0.x, ad0.y, ad0.z, ad0.w, ad1.x, ad1.y, ad1.z, ad1.w};
  int rr[8] = {ar0.x, ar0.y, ar0.z, ar0.w, ar1.x, ar1.y, ar1.z, ar1.w};
  int ll[8] = {al0.x, al0.y, al0.z, al0.w, al1.x, al1.y, al1.z, al1.w};
  unsigned char m[8] __attribute__((aligned(8)));
#pragma unroll
  for (int k = 0; k < 8; ++k)
    m[k] = (unsigned char)((u[k] ? 1u : 0u) | (dn[k] ? 2u : 0u) | (rr[k] ? 4u : 0u) | (ll[k] ? 8u : 0u));
  *(uint2*)&nibR[base] = *(uint2*)m;
  int it = i >> 4, jw = jb >> 5;
  int lane = ((jb >> 3) & 3) * 16 + (i & 15);
  *(uint2*)&nibF[((it * 32 + jw) * 64 + lane) * 8] = *(uint2*)m;
}

// ---------------------------------------------------------------------------
// K3: WhstF = frag-ordered bf16 of (Xb @ Wtsum[d])^T.
__global__ __launch_bounds__(256, 2) void k_whsum(const u16* __restrict__ X,
                                                  const u16* __restrict__ Wt,
                                                  u16* __restrict__ WhstF) {
  __shared__ u16 lA[128 * 32];
  __shared__ u16 lB[128 * 32];
  __shared__ u16 sC[128 * 136];
  int d = blockIdx.z;
  int m0 = blockIdx.y * 128;
  int o0 = blockIdx.x * 128;
  int t = threadIdx.x;
  int lane = t & 63, w = t >> 6;
  int wm = w >> 1, wn = w & 1;
  int r16 = lane & 15, quad = lane >> 4, q8 = quad * 8;
  f4 acc[4][4];
  const f4 fz = {0.f, 0.f, 0.f, 0.f};
#pragma unroll
  for (int i = 0; i < 4; ++i)
#pragma unroll
    for (int j = 0; j < 4; ++j) acc[i][j] = fz;

  const u16* Bp = Wt + d * 65536;
  for (int k0 = 0; k0 < 256; k0 += 32) {
    uint4 va[2], vb[2];
#pragma unroll
    for (int i = 0; i < 2; ++i) {
      int c = i * 256 + t;
      int row = c >> 2, ko = (c & 3) * 8;
      va[i] = *(const uint4*)&X[(size_t)(m0 + row) * 256 + k0 + ko];
      vb[i] = *(const uint4*)&Bp[(o0 + row) * 256 + k0 + ko];
    }
    __syncthreads();
#pragma unroll
    for (int i = 0; i < 2; ++i) {
      int c = i * 256 + t;
      *(uint4*)&lA[c * 8] = va[i];
      *(uint4*)&lB[c * 8] = vb[i];
    }
    __syncthreads();
    bf8 af[4], bfr[4];
#pragma unroll
    for (int tm = 0; tm < 4; ++tm)
      af[tm] = *(const bf8*)&lA[(wm * 64 + tm * 16 + r16) * 32 + q8];
#pragma unroll
    for (int tn = 0; tn < 4; ++tn)
      bfr[tn] = *(const bf8*)&lB[(wn * 64 + tn * 16 + r16) * 32 + q8];
#pragma unroll
    for (int tm = 0; tm < 4; ++tm)
#pragma unroll
      for (int tn = 0; tn < 4; ++tn)
        acc[tm][tn] = __builtin_amdgcn_mfma_f32_16x16x32_bf16(
            af[tm], bfr[tn], acc[tm][tn], 0, 0, 0);
  }
#pragma unroll
  for (int tm = 0; tm < 4; ++tm) {
#pragma unroll
    for (int tn = 0; tn < 4; ++tn) {
      int o = wn * 64 + tn * 16 + r16;
      int n = wm * 64 + tm * 16 + quad * 4;
      u16 p[4] __attribute__((aligned(8)));
#pragma unroll
      for (int r = 0; r < 4; ++r) p[r] = f2bf(acc[tm][tn][r]);
      *(uint2*)&sC[o * 136 + n] = *(uint2*)p;
    }
  }
  __syncthreads();
  int b = m0 >> 10;
  int nlo = m0 & 1023;
  int dbbase = d * 8 + b;
  int otg0 = o0 >> 4, jwg0 = nlo >> 5;
#pragma unroll
  for (int cc = 0; cc < 8; ++cc) {
    int c = cc * 256 + t;
    int p = c >> 6, l = c & 63;
    int ot_l = p >> 2, jw_l = p & 3;
    int o_l = ot_l * 16 + (l & 15);
    int j_l = jw_l * 32 + (l >> 4) * 8;
    uint4 v = *(const uint4*)&sC[o_l * 136 + j_l];
    int off = (((dbbase * 16 + otg0 + ot_l) * 32 + jwg0 + jw_l) * 64 + l) * 8;
    *(uint4*)&WhstF[off] = v;
  }
}

// ---------------------------------------------------------------------------
// K5: softmax -> alphaF (frag-ordered bf16). ed cached in LDS; single pass.
__global__ __launch_bounds__(256) void k_softmax(const float* __restrict__ es,
                                                 const float* __restrict__ ed,
                                                 const unsigned char* __restrict__ nibR,
                                                 u16* __restrict__ alphaF) {
  __shared__ float sEd[4 * 1024];
  __shared__ u16 sAl[16][1032];
  __shared__ float srs[16];
  int it = blockIdx.x, b = blockIdx.y;
  int t = threadIdx.x, lane = t & 63, w = t >> 6;
  const float NINF = -__builtin_inff();
#pragma unroll
  for (int c = 0; c < 4; ++c) {
    int q = c * 256 + t;
    int d = q >> 8, jc = (q & 255) * 4;
    *(float4*)&sEd[d * 1024 + jc] = *(const float4*)&ed[(size_t)(d * 8 + b) * 1024 + jc];
  }
  __syncthreads();
  for (int rr = 0; rr < 4; ++rr) {
    int r = w * 4 + rr;
    int i = it * 16 + r;
    float e0 = es[(0 * 8 + b) * 1024 + i];
    float e1 = es[(1 * 8 + b) * 1024 + i];
    float e2 = es[(2 * 8 + b) * 1024 + i];
    float e3 = es[(3 * 8 + b) * 1024 + i];
    unsigned mbv[16];
#pragma unroll
    for (int k = 0; k < 16; ++k) mbv[k] = nibR[i * 1024 + k * 64 + lane];
    float e[16];
    float mx = NINF;
#pragma unroll
    for (int k = 0; k < 16; ++k) {
      unsigned m = mbv[k];
      int d = m ? (31 - __clz((int)m)) : 0;
      float esd = d == 0 ? e0 : d == 1 ? e1 : d == 2 ? e2 : e3;
      float z = esd + sEd[d * 1024 + k * 64 + lane];
      float lz = z > 0.0f ? z : 0.01f * z;
      e[k] = m ? lz : NINF;
      mx = fmaxf(mx, e[k]);
    }
    for (int off = 32; off; off >>= 1) mx = fmaxf(mx, __shfl_xor(mx, off));
    float s = 0.f;
#pragma unroll
    for (int k = 0; k < 16; ++k) {
      float p = exp2f((e[k] - mx) * 1.4426950408889634f);
      s += p;
      sAl[r][k * 64 + lane] = f2bf(p);
    }
    for (int off = 32; off; off >>= 1) s += __shfl_xor(s, off);
    if (lane == 0) srs[r] = 1.0f / s;
  }
  __syncthreads();
#pragma unroll
  for (int cc = 0; cc < 8; ++cc) {
    int c = cc * 256 + t;
    int jw = c >> 6, l = c & 63;
    int i_l = l & 15;
    int j_l = jw * 32 + (l >> 4) * 8;
    uint4 v = *(const uint4*)&sAl[i_l][j_l];
    float rs = srs[i_l];
    u16 pk[8] __attribute__((aligned(16)));
    u32 wv[4] = {v.x, v.y, v.z, v.w};
#pragma unroll
    for (int k = 0; k < 4; ++k) {
      pk[k * 2] = f2bf(bf2f((u16)(wv[k] & 0xFFFFu)) * rs);
      pk[k * 2 + 1] = f2bf(bf2f((u16)(wv[k] >> 16)) * rs);
    }
    int off = (((b * 64 + it) * 32 + jw) * 64 + l) * 8;
    *(uint4*)&alphaF[off] = *(uint4*)pk;
  }
}

// ---------------------------------------------------------------------------
// K6 (R8): deepened pipeline — B 4-slot rotation with 3-step lookahead
// (~270 cyc > L2 ~200), A/nib double-buffered one js (4 steps) ahead.
// VGPRs are free here: occupancy is dispatch-limited (512 blocks = 2/CU).
__global__ __launch_bounds__(256, 2) void k_agg(const u16* __restrict__ alphaF,
                                                const unsigned char* __restrict__ nibF,
                                                const u16* __restrict__ WhstF,
                                                u16* __restrict__ part) {
  int ob2 = blockIdx.x;        // 2: o-half (8 o-tiles each)
  int bz = blockIdx.y;         // 32: b*4 + ks
  int iz = blockIdx.z;         // 8: i-tile-128
  int b = bz >> 2, ks = bz & 3;
  int t = threadIdx.x, lane = t & 63, w = t >> 6;
  int wm = w >> 1, wn = w & 1;
  int r16 = lane & 15, quad = lane >> 4;
  int itb = iz * 8 + wm * 4;
  int otb = ob2 * 8 + wn * 4;
  int jw0 = ks * 8;

  int aoff[4], noff[4], bo[4];
#pragma unroll
  for (int tm = 0; tm < 4; ++tm) {
    aoff[tm] = (((b * 64 + itb + tm) * 32 + jw0) * 64 + lane) * 8;
    noff[tm] = (((itb + tm) * 32 + jw0) * 64 + lane) * 8;
  }
#pragma unroll
  for (int d = 0; d < 4; ++d)
    bo[d] = ((((d * 8 + b) * 16 + otb) * 32 + jw0) * 64 + lane) * 8;

  f4 acc[4][4];
  const f4 fz = {0.f, 0.f, 0.f, 0.f};
#pragma unroll
  for (int i = 0; i < 4; ++i)
#pragma unroll
    for (int j = 0; j < 4; ++j) acc[i][j] = fz;

  uint4 A[2][4];
  uint2 Nn[2][4];
  uint4 Bb[4][4];
  union U { uint4 u; bf8 h; };

#pragma unroll
  for (int tm = 0; tm < 4; ++tm) {
    A[0][tm] = *(const uint4*)&alphaF[aoff[tm]];
    Nn[0][tm] = *(const uint2*)&nibF[noff[tm]];
  }
  // prime B pipeline: steps 0..2 (slots 0..2)
#pragma unroll
  for (int s = 0; s < 3; ++s)
#pragma unroll
    for (int tn = 0; tn < 4; ++tn)
      Bb[s][tn] = *(const uint4*)&WhstF[bo[s & 3] + (s >> 2) * 512 + tn * 16384];

#pragma unroll
  for (int js = 0; js < 8; ++js) {
    int cs = js & 1;
    if (js < 7) {
#pragma unroll
      for (int tm = 0; tm < 4; ++tm) {
        A[cs ^ 1][tm] = *(const uint4*)&alphaF[aoff[tm] + (js + 1) * 512];
        Nn[cs ^ 1][tm] = *(const uint2*)&nibF[noff[tm] + (js + 1) * 512];
      }
    }
#pragma unroll
    for (int d = 0; d < 4; ++d) {
      int s = js * 4 + d;
      if (s + 3 < 32) {
        int js3 = (s + 3) >> 2, d3 = (s + 3) & 3;
#pragma unroll
        for (int tn = 0; tn < 4; ++tn)
          Bb[(s + 3) & 3][tn] = *(const uint4*)&WhstF[bo[d3] + js3 * 512 + tn * 16384];
      }
      U af[4];
#pragma unroll
      for (int tm = 0; tm < 4; ++tm) {
        uint2 mb = Nn[cs][tm];
        u32 e0 = ((mb.x >> d) & 0x01010101u) * 0xFFu;
        u32 e1 = ((mb.y >> d) & 0x01010101u) * 0xFFu;
        af[tm].u.x = A[cs][tm].x & dup01(e0);
        af[tm].u.y = A[cs][tm].y & dup23(e0);
        af[tm].u.z = A[cs][tm].z & dup01(e1);
        af[tm].u.w = A[cs][tm].w & dup23(e1);
      }
#pragma unroll
      for (int tm = 0; tm < 4; ++tm)
#pragma unroll
        for (int tn = 0; tn < 4; ++tn) {
          U bb; bb.u = Bb[s & 3][tn];
          acc[tm][tn] = __builtin_amdgcn_mfma_f32_16x16x32_bf16(
              af[tm].h, bb.h, acc[tm][tn], 0, 0, 0);
        }
    }
  }
  u16* P = part + (size_t)ks * 2097152;
#pragma unroll
  for (int tm = 0; tm < 4; ++tm) {
#pragma unroll
    for (int tn = 0; tn < 4; ++tn) {
      int irow = (itb + tm) * 16 + quad * 4;
      int go = (otb + tn) * 16 + r16;
#pragma unroll
      for (int r = 0; r < 4; ++r)
        P[((size_t)b * 1024 + irow + r) * 256 + go] = f2bf(acc[tm][tn][r]);
    }
  }
}

// ---------------------------------------------------------------------------
// K7: out = 0.5 * sum_ks part[ks]  (bf16 -> fp32)
__global__ void k_reduce(const u16* __restrict__ part, float* __restrict__ out) {
  int idx = (blockIdx.x * 256 + threadIdx.x) * 8;
  float s[8];
#pragma unroll
  for (int k = 0; k < 8; ++k) s[k] = 0.f;
#pragma unroll
  for (int ks = 0; ks < 4; ++ks) {
    uint4 v = *(const uint4*)&part[(size_t)ks * 2097152 + idx];
    u32 ww[4] = {v.x, v.y, v.z, v.w};
#pragma unroll
    for (int k = 0; k < 4; ++k) {
      union { u32 i; float f; } lo, hi;
      lo.i = (ww[k] & 0xFFFFu) << 16;
      hi.i = ww[k] & 0xFFFF0000u;
      s[k * 2] += lo.f;
      s[k * 2 + 1] += hi.f;
    }
  }
  float4 o0 = {0.5f * s[0], 0.5f * s[1], 0.5f * s[2], 0.5f * s[3]};
  float4 o1 = {0.5f * s[4], 0.5f * s[5], 0.5f * s[6], 0.5f * s[7]};
  *(float4*)&out[idx] = o0;
  *(float4*)&out[idx + 4] = o1;
}

// ---------------------------------------------------------------------------
extern "C" void kernel_launch(void* const* d_in, const int* in_sizes, int n_in,
                              void* d_out, int out_size, void* d_ws, size_t ws_size,
                              hipStream_t stream) {
  const float* x = (const float*)d_in[0];
  const int* AU = (const int*)d_in[1];
  const int* AD = (const int*)d_in[2];
  const int* AR = (const int*)d_in[3];
  const int* AL = (const int*)d_in[4];
  const float* W = (const float*)d_in[5];
  const float* a = (const float*)d_in[6];
  float* out = (float*)d_out;

  char* ws = (char*)d_ws;
  u16* Wt = (u16*)(ws + 0);                      // 512 KB
  float* vsrc = (float*)(ws + 524288);           //   4 KB
  float* vdst = (float*)(ws + 528384);           //   4 KB
  float* es = (float*)(ws + 532480);             // 128 KB
  float* ed = (float*)(ws + 663552);             // 128 KB
  unsigned char* nibR = (unsigned char*)(ws + 794624);   // 1 MB
  unsigned char* nibF = (unsigned char*)(ws + 1843200);  // 1 MB
  u16* xb = (u16*)(ws + 2891776);                //   4 MB
  u16* WhstF = (u16*)(ws + 7086080);             //  16 MB
  u16* alphaF = (u16*)(ws + 23863296);           //  16 MB
  u16* part = (u16*)(ws + 40640512);             //  16 MB
  if (ws_size < 57417728) return;

  hipLaunchKernelGGL(k_transpose, dim3(16, 4), dim3(256), 0, stream, W, Wt);
  hipLaunchKernelGGL(k_vsd, dim3(1024), dim3(256), 0, stream, W, a, vsrc, vdst);
  hipLaunchKernelGGL(k_edots, dim3(512), dim3(256), 0, stream, x, vsrc, vdst, es, ed, xb);
  hipLaunchKernelGGL(k_mask, dim3(512), dim3(256), 0, stream, AU, AD, AR, AL, nibR, nibF);
  hipLaunchKernelGGL(k_whsum, dim3(2, 64, 4), dim3(256), 0, stream, xb, Wt, WhstF);
  hipLaunchKernelGGL(k_softmax, dim3(64, 8), dim3(256), 0, stream, es, ed, nibR, alphaF);
  hipLaunchKernelGGL(k_agg, dim3(2, 32, 8), dim3(256), 0, stream, alphaF, nibF, WhstF, part);
  hipLaunchKernelGGL(k_reduce, dim3(1024), dim3(256), 0, stream, part, out);
}

// Round 9
// 150.471 us; speedup vs baseline: 3.5594x; 1.0714x over previous
//
#include <hip/hip_runtime.h>

// Problem constants
#define B_ 8
#define N_ 1024
#define F_ 256
#define O_ 256

typedef unsigned short u16;
typedef unsigned int u32;
typedef __attribute__((ext_vector_type(8))) short bf8;   // 8 bf16 (4 VGPRs) MFMA frag
typedef __attribute__((ext_vector_type(4))) float f4;    // 4 fp32 MFMA acc

__device__ __forceinline__ u16 f2bf(float f) {
  union { float f; u32 u; } c; c.f = f;
  u32 u = c.u;
  u32 r = u + 0x7FFFu + ((u >> 16) & 1u);  // RNE
  return (u16)(r >> 16);
}
__device__ __forceinline__ float bf2f(u16 u) {
  union { u32 i; float f; } c; c.i = ((u32)u) << 16; return c.f;
}

#if defined(__has_builtin)
#if __has_builtin(__builtin_amdgcn_perm)
#define HAVE_PERM 1
#endif
#endif
__device__ __forceinline__ u32 dup01(u32 e) {  // bytes (b0,b0,b1,b1)
#ifdef HAVE_PERM
  return __builtin_amdgcn_perm(e, e, 0x01010000u);
#else
  return (e & 0xFFu) * 0x0101u + (e & 0xFF00u) * 0x010100u;
#endif
}
__device__ __forceinline__ u32 dup23(u32 e) {  // bytes (b2,b2,b3,b3)
#ifdef HAVE_PERM
  return __builtin_amdgcn_perm(e, e, 0x03030202u);
#else
  return ((e >> 16) & 0xFFu) * 0x0101u + ((e >> 16) & 0xFF00u) * 0x010100u;
#endif
}

// ---------------------------------------------------------------------------
// K_prep: fused {W transpose+head-sum} | {vsrc/vdst dots} | {nibble masks}.
// Partitioned by blockIdx.x: [0,64) transpose, [64,1088) vsd, [1088,1600) mask.
__global__ __launch_bounds__(256) void k_prep(const float* __restrict__ W,
                                              const float* __restrict__ a,
                                              u16* __restrict__ Wt,
                                              float* __restrict__ vsrc,
                                              float* __restrict__ vdst,
                                              const int* __restrict__ AU,
                                              const int* __restrict__ AD,
                                              const int* __restrict__ AR,
                                              const int* __restrict__ AL,
                                              unsigned char* __restrict__ nibR,
                                              unsigned char* __restrict__ nibF) {
  __shared__ u16 t[64][72];
  __shared__ float red[2][4];
  int bx = blockIdx.x;
  int tdx = threadIdx.x;
  if (bx < 64) {
    // ---- transpose: Wt[d][o][f] = bf16(W[d,0]+W[d,1])^T
    int d = bx >> 4, tile = bx & 15;
    int f0 = (tile >> 2) * 64, o0 = (tile & 3) * 64;
    const float* src0 = W + (d * 2 + 0) * 65536;
    const float* src1 = W + (d * 2 + 1) * 65536;
    u16* dst = Wt + d * 65536;
    for (int i = 0; i < 2; ++i) {
      int c = i * 256 + tdx;
      int row = c >> 3, cc = (c & 7) * 8;
      int base = (f0 + row) * 256 + o0 + cc;
      float4 a0 = *(const float4*)&src0[base];
      float4 a1 = *(const float4*)&src0[base + 4];
      float4 b0 = *(const float4*)&src1[base];
      float4 b1 = *(const float4*)&src1[base + 4];
      u16 tmp[8] __attribute__((aligned(16)));
      tmp[0] = f2bf(a0.x + b0.x); tmp[1] = f2bf(a0.y + b0.y);
      tmp[2] = f2bf(a0.z + b0.z); tmp[3] = f2bf(a0.w + b0.w);
      tmp[4] = f2bf(a1.x + b1.x); tmp[5] = f2bf(a1.y + b1.y);
      tmp[6] = f2bf(a1.z + b1.z); tmp[7] = f2bf(a1.w + b1.w);
      *(uint4*)&t[row][cc] = *(uint4*)tmp;
    }
    __syncthreads();
    for (int i = 0; i < 2; ++i) {
      int c = i * 256 + tdx;
      int orow = c >> 3, fc = (c & 7) * 8;
      u16 v[8] __attribute__((aligned(16)));
#pragma unroll
      for (int k = 0; k < 8; ++k) v[k] = t[fc + k][orow];
      *(uint4*)&dst[(o0 + orow) * 256 + f0 + fc] = *(uint4*)v;
    }
  } else if (bx < 1088) {
    // ---- vsd
    int blk = bx - 64;
    int d = blk >> 8, f = blk & 255;
    int o = tdx;
    int dh = d * 2 + 1;
    float w = W[(dh * 256 + f) * 256 + o];
    float as = a[dh * 512 + o];
    float ad = a[dh * 512 + 256 + o];
    float ps = w * as, pd = w * ad;
    for (int off = 32; off; off >>= 1) {
      ps += __shfl_down(ps, off);
      pd += __shfl_down(pd, off);
    }
    int lane = o & 63, w4 = o >> 6;
    if (lane == 0) { red[0][w4] = ps; red[1][w4] = pd; }
    __syncthreads();
    if (o == 0) vsrc[d * 256 + f] = red[0][0] + red[0][1] + red[0][2] + red[0][3];
    if (o == 1) vdst[d * 256 + f] = red[1][0] + red[1][1] + red[1][2] + red[1][3];
  } else {
    // ---- mask
    int idx = (bx - 1088) * 256 + tdx;  // 131072: i*128 + j/8
    int i = idx >> 7;
    int jb = (idx & 127) * 8;
    int base = i * 1024 + jb;
    int4 au0 = *(const int4*)&AU[base], au1 = *(const int4*)&AU[base + 4];
    int4 ad0 = *(const int4*)&AD[base], ad1 = *(const int4*)&AD[base + 4];
    int4 ar0 = *(const int4*)&AR[base], ar1 = *(const int4*)&AR[base + 4];
    int4 al0 = *(const int4*)&AL[base], al1 = *(const int4*)&AL[base + 4];
    int u[8] = {au0.x, au0.y, au0.z, au0.w, au1.x, au1.y, au1.z, au1.w};
    int dn[8] = {ad0.x, ad0.y, ad0.z, ad0.w, ad1.x, ad1.y, ad1.z, ad1.w};
    int rr[8] = {ar0.x, ar0.y, ar0.z, ar0.w, ar1.x, ar1.y, ar1.z, ar1.w};
    int ll[8] = {al0.x, al0.y, al0.z, al0.w, al1.x, al1.y, al1.z, al1.w};
    unsigned char m[8] __attribute__((aligned(8)));
#pragma unroll
    for (int k = 0; k < 8; ++k)
      m[k] = (unsigned char)((u[k] ? 1u : 0u) | (dn[k] ? 2u : 0u) | (rr[k] ? 4u : 0u) | (ll[k] ? 8u : 0u));
    *(uint2*)&nibR[base] = *(uint2*)m;
    int it = i >> 4, jw = jb >> 5;
    int lane = ((jb >> 3) & 3) * 16 + (i & 15);
    *(uint2*)&nibF[((it * 32 + jw) * 64 + lane) * 8] = *(uint2*)m;
  }
}

// ---------------------------------------------------------------------------
// K2: wave-per-4-rows e-dots + xb emit.
__global__ __launch_bounds__(256) void k_edots(const float* __restrict__ x,
                                               const float* __restrict__ vsrc,
                                               const float* __restrict__ vdst,
                                               float* __restrict__ es,
                                               float* __restrict__ ed,
                                               u16* __restrict__ xb) {
  int t = threadIdx.x, lane = t & 63, w = t >> 6;
  int f4i = lane * 4;
  float4 vs[4], vd[4];
#pragma unroll
  for (int d = 0; d < 4; ++d) {
    vs[d] = *(const float4*)&vsrc[d * 256 + f4i];
    vd[d] = *(const float4*)&vdst[d * 256 + f4i];
  }
  int row0 = blockIdx.x * 16 + w * 4;  // 512 blocks x 16 rows
  for (int rr = 0; rr < 4; ++rr) {
    int row = row0 + rr;
    float4 xv = *(const float4*)&x[(size_t)row * 256 + f4i];
    u16 pk[4] __attribute__((aligned(8)));
    pk[0] = f2bf(xv.x); pk[1] = f2bf(xv.y); pk[2] = f2bf(xv.z); pk[3] = f2bf(xv.w);
    *(uint2*)&xb[(size_t)row * 256 + f4i] = *(uint2*)pk;
    float p[8];
#pragma unroll
    for (int d = 0; d < 4; ++d) {
      p[d] = xv.x * vs[d].x + xv.y * vs[d].y + xv.z * vs[d].z + xv.w * vs[d].w;
      p[4 + d] = xv.x * vd[d].x + xv.y * vd[d].y + xv.z * vd[d].z + xv.w * vd[d].w;
    }
#pragma unroll
    for (int v = 0; v < 8; ++v)
      for (int off = 32; off; off >>= 1) p[v] += __shfl_xor(p[v], off);
    if (lane == 0) {
      int b = row >> 10, n = row & 1023;
#pragma unroll
      for (int d = 0; d < 4; ++d) {
        es[(d * 8 + b) * 1024 + n] = p[d];
        ed[(d * 8 + b) * 1024 + n] = p[4 + d];
      }
    }
  }
}

// ---------------------------------------------------------------------------
// K_mid: fused {whsum MFMA GEMM} | {softmax}. Partition: blockIdx.x<512 whsum,
// else softmax. 51 KB shared arena (max of branches); >=3 blocks/CU by LDS.
__global__ __launch_bounds__(256, 2) void k_mid(const u16* __restrict__ X,
                                                const u16* __restrict__ Wt,
                                                u16* __restrict__ WhstF,
                                                const float* __restrict__ es,
                                                const float* __restrict__ ed,
                                                const unsigned char* __restrict__ nibR,
                                                u16* __restrict__ alphaF) {
  __shared__ char smem[51200];
  int bx = blockIdx.x;
  int t = threadIdx.x;
  int lane = t & 63, w = t >> 6;
  if (bx < 512) {
    // ---- whsum: WhstF = frag-ordered bf16 of (Xb @ Wtsum[d])^T
    u16* lA = (u16*)smem;                   //  8192 B
    u16* lB = (u16*)(smem + 8192);          //  8192 B
    u16* sC = (u16*)(smem + 16384);         // 34816 B (128x136 u16)
    int xo = bx & 1;
    int m0 = ((bx >> 1) & 63) * 128;
    int d = bx >> 7;
    int o0 = xo * 128;
    int wm = w >> 1, wn = w & 1;
    int r16 = lane & 15, quad = lane >> 4, q8 = quad * 8;
    f4 acc[4][4];
    const f4 fz = {0.f, 0.f, 0.f, 0.f};
#pragma unroll
    for (int i = 0; i < 4; ++i)
#pragma unroll
      for (int j = 0; j < 4; ++j) acc[i][j] = fz;

    const u16* Bp = Wt + d * 65536;
    for (int k0 = 0; k0 < 256; k0 += 32) {
      uint4 va[2], vb[2];
#pragma unroll
      for (int i = 0; i < 2; ++i) {
        int c = i * 256 + t;
        int row = c >> 2, ko = (c & 3) * 8;
        va[i] = *(const uint4*)&X[(size_t)(m0 + row) * 256 + k0 + ko];
        vb[i] = *(const uint4*)&Bp[(o0 + row) * 256 + k0 + ko];
      }
      __syncthreads();
#pragma unroll
      for (int i = 0; i < 2; ++i) {
        int c = i * 256 + t;
        *(uint4*)&lA[c * 8] = va[i];
        *(uint4*)&lB[c * 8] = vb[i];
      }
      __syncthreads();
      bf8 af[4], bfr[4];
#pragma unroll
      for (int tm = 0; tm < 4; ++tm)
        af[tm] = *(const bf8*)&lA[(wm * 64 + tm * 16 + r16) * 32 + q8];
#pragma unroll
      for (int tn = 0; tn < 4; ++tn)
        bfr[tn] = *(const bf8*)&lB[(wn * 64 + tn * 16 + r16) * 32 + q8];
#pragma unroll
      for (int tm = 0; tm < 4; ++tm)
#pragma unroll
        for (int tn = 0; tn < 4; ++tn)
          acc[tm][tn] = __builtin_amdgcn_mfma_f32_16x16x32_bf16(
              af[tm], bfr[tn], acc[tm][tn], 0, 0, 0);
    }
#pragma unroll
    for (int tm = 0; tm < 4; ++tm) {
#pragma unroll
      for (int tn = 0; tn < 4; ++tn) {
        int o = wn * 64 + tn * 16 + r16;
        int n = wm * 64 + tm * 16 + quad * 4;
        u16 p[4] __attribute__((aligned(8)));
#pragma unroll
        for (int r = 0; r < 4; ++r) p[r] = f2bf(acc[tm][tn][r]);
        *(uint2*)&sC[o * 136 + n] = *(uint2*)p;
      }
    }
    __syncthreads();
    int b = m0 >> 10;
    int nlo = m0 & 1023;
    int dbbase = d * 8 + b;
    int otg0 = o0 >> 4, jwg0 = nlo >> 5;
#pragma unroll
    for (int cc = 0; cc < 8; ++cc) {
      int c = cc * 256 + t;
      int p = c >> 6, l = c & 63;
      int ot_l = p >> 2, jw_l = p & 3;
      int o_l = ot_l * 16 + (l & 15);
      int j_l = jw_l * 32 + (l >> 4) * 8;
      uint4 v = *(const uint4*)&sC[o_l * 136 + j_l];
      int off = (((dbbase * 16 + otg0 + ot_l) * 32 + jwg0 + jw_l) * 64 + l) * 8;
      *(uint4*)&WhstF[off] = v;
    }
  } else {
    // ---- softmax -> alphaF (frag-ordered). ed cached in LDS; single pass.
    float* sEd = (float*)smem;                       // 16384 B
    u16 (*sAl)[1032] = (u16(*)[1032])(smem + 16384); // 33024 B
    float* srs = (float*)(smem + 49408);             //    64 B
    int sx = bx - 512;
    int it = sx & 63, b = sx >> 6;
    const float NINF = -__builtin_inff();
#pragma unroll
    for (int c = 0; c < 4; ++c) {
      int q = c * 256 + t;
      int d = q >> 8, jc = (q & 255) * 4;
      *(float4*)&sEd[d * 1024 + jc] = *(const float4*)&ed[(size_t)(d * 8 + b) * 1024 + jc];
    }
    __syncthreads();
    for (int rr = 0; rr < 4; ++rr) {
      int r = w * 4 + rr;
      int i = it * 16 + r;
      float e0 = es[(0 * 8 + b) * 1024 + i];
      float e1 = es[(1 * 8 + b) * 1024 + i];
      float e2 = es[(2 * 8 + b) * 1024 + i];
      float e3 = es[(3 * 8 + b) * 1024 + i];
      unsigned mbv[16];
#pragma unroll
      for (int k = 0; k < 16; ++k) mbv[k] = nibR[i * 1024 + k * 64 + lane];
      float e[16];
      float mx = NINF;
#pragma unroll
      for (int k = 0; k < 16; ++k) {
        unsigned m = mbv[k];
        int d = m ? (31 - __clz((int)m)) : 0;
        float esd = d == 0 ? e0 : d == 1 ? e1 : d == 2 ? e2 : e3;
        float z = esd + sEd[d * 1024 + k * 64 + lane];
        float lz = z > 0.0f ? z : 0.01f * z;
        e[k] = m ? lz : NINF;
        mx = fmaxf(mx, e[k]);
      }
      for (int off = 32; off; off >>= 1) mx = fmaxf(mx, __shfl_xor(mx, off));
      float s = 0.f;
#pragma unroll
      for (int k = 0; k < 16; ++k) {
        float p = exp2f((e[k] - mx) * 1.4426950408889634f);
        s += p;
        sAl[r][k * 64 + lane] = f2bf(p);
      }
      for (int off = 32; off; off >>= 1) s += __shfl_xor(s, off);
      if (lane == 0) srs[r] = 1.0f / s;
    }
    __syncthreads();
#pragma unroll
    for (int cc = 0; cc < 8; ++cc) {
      int c = cc * 256 + t;
      int jw = c >> 6, l = c & 63;
      int i_l = l & 15;
      int j_l = jw * 32 + (l >> 4) * 8;
      uint4 v = *(const uint4*)&sAl[i_l][j_l];
      float rs = srs[i_l];
      u16 pk[8] __attribute__((aligned(16)));
      u32 wv[4] = {v.x, v.y, v.z, v.w};
#pragma unroll
      for (int k = 0; k < 4; ++k) {
        pk[k * 2] = f2bf(bf2f((u16)(wv[k] & 0xFFFFu)) * rs);
        pk[k * 2 + 1] = f2bf(bf2f((u16)(wv[k] >> 16)) * rs);
      }
      int off = (((b * 64 + it) * 32 + jw) * 64 + l) * 8;
      *(uint4*)&alphaF[off] = *(uint4*)pk;
    }
  }
}

// ---------------------------------------------------------------------------
// K6: deep-pipelined frag-ordered masked-GEMM aggregation (unchanged from R8).
__global__ __launch_bounds__(256, 2) void k_agg(const u16* __restrict__ alphaF,
                                                const unsigned char* __restrict__ nibF,
                                                const u16* __restrict__ WhstF,
                                                u16* __restrict__ part) {
  int ob2 = blockIdx.x;        // 2: o-half (8 o-tiles each)
  int bz = blockIdx.y;         // 32: b*4 + ks
  int iz = blockIdx.z;         // 8: i-tile-128
  int b = bz >> 2, ks = bz & 3;
  int t = threadIdx.x, lane = t & 63, w = t >> 6;
  int wm = w >> 1, wn = w & 1;
  int r16 = lane & 15, quad = lane >> 4;
  int itb = iz * 8 + wm * 4;
  int otb = ob2 * 8 + wn * 4;
  int jw0 = ks * 8;

  int aoff[4], noff[4], bo[4];
#pragma unroll
  for (int tm = 0; tm < 4; ++tm) {
    aoff[tm] = (((b * 64 + itb + tm) * 32 + jw0) * 64 + lane) * 8;
    noff[tm] = (((itb + tm) * 32 + jw0) * 64 + lane) * 8;
  }
#pragma unroll
  for (int d = 0; d < 4; ++d)
    bo[d] = ((((d * 8 + b) * 16 + otb) * 32 + jw0) * 64 + lane) * 8;

  f4 acc[4][4];
  const f4 fz = {0.f, 0.f, 0.f, 0.f};
#pragma unroll
  for (int i = 0; i < 4; ++i)
#pragma unroll
    for (int j = 0; j < 4; ++j) acc[i][j] = fz;

  uint4 A[2][4];
  uint2 Nn[2][4];
  uint4 Bb[4][4];
  union U { uint4 u; bf8 h; };

#pragma unroll
  for (int tm = 0; tm < 4; ++tm) {
    A[0][tm] = *(const uint4*)&alphaF[aoff[tm]];
    Nn[0][tm] = *(const uint2*)&nibF[noff[tm]];
  }
#pragma unroll
  for (int s = 0; s < 3; ++s)
#pragma unroll
    for (int tn = 0; tn < 4; ++tn)
      Bb[s][tn] = *(const uint4*)&WhstF[bo[s & 3] + (s >> 2) * 512 + tn * 16384];

#pragma unroll
  for (int js = 0; js < 8; ++js) {
    int cs = js & 1;
    if (js < 7) {
#pragma unroll
      for (int tm = 0; tm < 4; ++tm) {
        A[cs ^ 1][tm] = *(const uint4*)&alphaF[aoff[tm] + (js + 1) * 512];
        Nn[cs ^ 1][tm] = *(const uint2*)&nibF[noff[tm] + (js + 1) * 512];
      }
    }
#pragma unroll
    for (int d = 0; d < 4; ++d) {
      int s = js * 4 + d;
      if (s + 3 < 32) {
        int js3 = (s + 3) >> 2, d3 = (s + 3) & 3;
#pragma unroll
        for (int tn = 0; tn < 4; ++tn)
          Bb[(s + 3) & 3][tn] = *(const uint4*)&WhstF[bo[d3] + js3 * 512 + tn * 16384];
      }
      U af[4];
#pragma unroll
      for (int tm = 0; tm < 4; ++tm) {
        uint2 mb = Nn[cs][tm];
        u32 e0 = ((mb.x >> d) & 0x01010101u) * 0xFFu;
        u32 e1 = ((mb.y >> d) & 0x01010101u) * 0xFFu;
        af[tm].u.x = A[cs][tm].x & dup01(e0);
        af[tm].u.y = A[cs][tm].y & dup23(e0);
        af[tm].u.z = A[cs][tm].z & dup01(e1);
        af[tm].u.w = A[cs][tm].w & dup23(e1);
      }
#pragma unroll
      for (int tm = 0; tm < 4; ++tm)
#pragma unroll
        for (int tn = 0; tn < 4; ++tn) {
          U bb; bb.u = Bb[s & 3][tn];
          acc[tm][tn] = __builtin_amdgcn_mfma_f32_16x16x32_bf16(
              af[tm].h, bb.h, acc[tm][tn], 0, 0, 0);
        }
    }
  }
  u16* P = part + (size_t)ks * 2097152;
#pragma unroll
  for (int tm = 0; tm < 4; ++tm) {
#pragma unroll
    for (int tn = 0; tn < 4; ++tn) {
      int irow = (itb + tm) * 16 + quad * 4;
      int go = (otb + tn) * 16 + r16;
#pragma unroll
      for (int r = 0; r < 4; ++r)
        P[((size_t)b * 1024 + irow + r) * 256 + go] = f2bf(acc[tm][tn][r]);
    }
  }
}

// ---------------------------------------------------------------------------
// K7: out = 0.5 * sum_ks part[ks]  (bf16 -> fp32)
__global__ void k_reduce(const u16* __restrict__ part, float* __restrict__ out) {
  int idx = (blockIdx.x * 256 + threadIdx.x) * 8;
  float s[8];
#pragma unroll
  for (int k = 0; k < 8; ++k) s[k] = 0.f;
#pragma unroll
  for (int ks = 0; ks < 4; ++ks) {
    uint4 v = *(const uint4*)&part[(size_t)ks * 2097152 + idx];
    u32 ww[4] = {v.x, v.y, v.z, v.w};
#pragma unroll
    for (int k = 0; k < 4; ++k) {
      union { u32 i; float f; } lo, hi;
      lo.i = (ww[k] & 0xFFFFu) << 16;
      hi.i = ww[k] & 0xFFFF0000u;
      s[k * 2] += lo.f;
      s[k * 2 + 1] += hi.f;
    }
  }
  float4 o0 = {0.5f * s[0], 0.5f * s[1], 0.5f * s[2], 0.5f * s[3]};
  float4 o1 = {0.5f * s[4], 0.5f * s[5], 0.5f * s[6], 0.5f * s[7]};
  *(float4*)&out[idx] = o0;
  *(float4*)&out[idx + 4] = o1;
}

// ---------------------------------------------------------------------------
extern "C" void kernel_launch(void* const* d_in, const int* in_sizes, int n_in,
                              void* d_out, int out_size, void* d_ws, size_t ws_size,
                              hipStream_t stream) {
  const float* x = (const float*)d_in[0];
  const int* AU = (const int*)d_in[1];
  const int* AD = (const int*)d_in[2];
  const int* AR = (const int*)d_in[3];
  const int* AL = (const int*)d_in[4];
  const float* W = (const float*)d_in[5];
  const float* a = (const float*)d_in[6];
  float* out = (float*)d_out;

  char* ws = (char*)d_ws;
  u16* Wt = (u16*)(ws + 0);                      // 512 KB
  float* vsrc = (float*)(ws + 524288);           //   4 KB
  float* vdst = (float*)(ws + 528384);           //   4 KB
  float* es = (float*)(ws + 532480);             // 128 KB
  float* ed = (float*)(ws + 663552);             // 128 KB
  unsigned char* nibR = (unsigned char*)(ws + 794624);   // 1 MB
  unsigned char* nibF = (unsigned char*)(ws + 1843200);  // 1 MB
  u16* xb = (u16*)(ws + 2891776);                //   4 MB
  u16* WhstF = (u16*)(ws + 7086080);             //  16 MB
  u16* alphaF = (u16*)(ws + 23863296);           //  16 MB
  u16* part = (u16*)(ws + 40640512);             //  16 MB
  if (ws_size < 57417728) return;

  hipLaunchKernelGGL(k_prep, dim3(1600), dim3(256), 0, stream,
                     W, a, Wt, vsrc, vdst, AU, AD, AR, AL, nibR, nibF);
  hipLaunchKernelGGL(k_edots, dim3(512), dim3(256), 0, stream, x, vsrc, vdst, es, ed, xb);
  hipLaunchKernelGGL(k_mid, dim3(1024), dim3(256), 0, stream,
                     xb, Wt, WhstF, es, ed, nibR, alphaF);
  hipLaunchKernelGGL(k_agg, dim3(2, 32, 8), dim3(256), 0, stream, alphaF, nibF, WhstF, part);
  hipLaunchKernelGGL(k_reduce, dim3(1024), dim3(256), 0, stream, part, out);
}